// Round 5
// baseline (292.795 us; speedup 1.0000x reference)
//
#include <hip/hip_runtime.h>

// GovernanceAwareAttention on MI355X (gfx950). Round 5.
// Governance bias is constant along key axis -> softmax invariant -> only
// `influence` needs gov_scores. bf16 MFMA projections + flash attention.
//
// R5: (1) native v_exp_f32 via __builtin_amdgcn_exp2f (libm exp2f was
// expanding to an OCML sequence -> VALUBusy 57%); (2) attention waves own 64
// queries (256-query blocks, grid 256, 1 block/CU): K/V LDS reads + staging
// amortize over 2x queries, MFMA/wave-iter 32->64 with DS reads unchanged;
// (3) projection GEMM double-buffered (prefetch-after-barrier), targeting
// the short-K (32-iter) barrier drain.

typedef unsigned short u16;
typedef __attribute__((ext_vector_type(8))) short bf16x8;   // 8 bf16 = 4 VGPR
typedef __attribute__((ext_vector_type(4))) float f32x4;
typedef __attribute__((ext_vector_type(16))) float f32x16;
typedef __attribute__((ext_vector_type(4))) u16 u16x4;
typedef __attribute__((ext_vector_type(4))) float float4v;
typedef __attribute__((ext_vector_type(2))) unsigned uint2v;

typedef const __attribute__((address_space(1))) void gvoid_t;
typedef __attribute__((address_space(3))) void lvoid_t;

__device__ __forceinline__ void gl_lds16(const void* g, void* l) {
  // async global->LDS, 16B/lane; LDS dest is wave-uniform base + lane*16
  __builtin_amdgcn_global_load_lds((gvoid_t*)g, (lvoid_t*)l, 16, 0, 0);
}

__device__ __forceinline__ u16 f2bf(float x) {  // RNE f32->bf16
  union { float f; unsigned u; } v; v.f = x;
  unsigned r = v.u + 0x7fffu + ((v.u >> 16) & 1u);
  return (u16)(r >> 16);
}
__device__ __forceinline__ float bf2f(u16 h) {
  union { unsigned u; float f; } v; v.u = ((unsigned)h) << 16; return v.f;
}
// pack two f32 -> two truncated bf16 in one v_perm_b32 (lo in low half)
__device__ __forceinline__ unsigned pk2(float hi, float lo) {
  union { float f; unsigned u; } a, b; a.f = hi; b.f = lo;
  return __builtin_amdgcn_perm(a.u, b.u, 0x07060302u);
}
__device__ __forceinline__ bf16x8 mk8(unsigned a, unsigned b, unsigned c, unsigned d) {
  union { unsigned u[4]; bf16x8 v; } x;
  x.u[0] = a; x.u[1] = b; x.u[2] = c; x.u[3] = d; return x.v;
}

#if defined(__has_builtin)
#if __has_builtin(__builtin_amdgcn_permlane32_swap)
#define HAVE_PLSWAP 1
#endif
#if __has_builtin(__builtin_amdgcn_exp2f)
#define EXP2(x) __builtin_amdgcn_exp2f(x)
#endif
#endif
#ifndef EXP2
#define EXP2(x) exp2f(x)
#endif

// a' = {a.lo, b.lo}, b' = {a.hi, b.hi}  (swap a's upper 32 lanes w/ b's lower)
__device__ __forceinline__ void plswap(unsigned& a, unsigned& b, int lane) {
#ifdef HAVE_PLSWAP
  uint2v r = __builtin_amdgcn_permlane32_swap(a, b, false, false);
  a = r.x; b = r.y;
#else
  unsigned ca = __builtin_amdgcn_ds_bpermute((lane ^ 32) << 2, a);
  unsigned cb = __builtin_amdgcn_ds_bpermute((lane ^ 32) << 2, b);
  unsigned na = (lane < 32) ? a : cb;
  unsigned nb = (lane < 32) ? ca : b;
  a = na; b = nb;
#endif
}

// ---------------- prep: hs->bf16, W->W^T bf16, gq partials ----------------
// grid 3136: [0,2048) conv_hs, [2048,3072) conv_w, [3072,3136) gq partials.
__global__ void prep(const float* __restrict__ hs,
                     const float* __restrict__ W0, const float* __restrict__ W1,
                     const float* __restrict__ W2, const float* __restrict__ W3,
                     const float* __restrict__ ge, const float* __restrict__ Wgq,
                     u16* __restrict__ hsB, u16* __restrict__ WB,
                     float* __restrict__ gq_part) {
  __shared__ __align__(16) u16 T[64][72];
  int bx = blockIdx.x, tid = threadIdx.x;
  if (bx < 2048) {                       // hs f32 [4096x1024] -> bf16, RNE
    int i = bx * 256 + tid;
    const float4v* in4 = (const float4v*)hs;
    float4v a = in4[i * 2], b = in4[i * 2 + 1];
    bf16x8 v;
    v[0] = (short)f2bf(a.x); v[1] = (short)f2bf(a.y);
    v[2] = (short)f2bf(a.z); v[3] = (short)f2bf(a.w);
    v[4] = (short)f2bf(b.x); v[5] = (short)f2bf(b.y);
    v[6] = (short)f2bf(b.z); v[7] = (short)f2bf(b.w);
    *(bf16x8*)&hsB[(size_t)i * 8] = v;
    return;
  }
  if (bx < 3072) {                       // W[k][n] -> WB[mat*1024+n][k], LDS xpose
    int idx = bx - 2048;
    int mat = idx >> 8, sub = idx & 255;
    const float* W = (mat == 0) ? W0 : (mat == 1) ? W1 : (mat == 2) ? W2 : W3;
    int k0 = (sub >> 4) * 64, n0 = (sub & 15) * 64;
#pragma unroll
    for (int p = 0; p < 4; ++p) {
      int chunk = p * 256 + tid;
      int row = chunk >> 4, cp = chunk & 15;
      float4v v = *(const float4v*)&W[(size_t)(k0 + row) * 1024 + n0 + cp * 4];
      u16x4 o; o.x = f2bf(v.x); o.y = f2bf(v.y); o.z = f2bf(v.z); o.w = f2bf(v.w);
      *(u16x4*)&T[row][cp * 4] = o;
    }
    __syncthreads();
#pragma unroll
    for (int p = 0; p < 2; ++p) {
      int chunk = p * 256 + tid;
      int nrow = chunk >> 3, cp = chunk & 7;
      bf16x8 v;
#pragma unroll
      for (int e = 0; e < 8; ++e) v[e] = (short)T[cp * 8 + e][nrow];
      *(bf16x8*)&WB[(size_t)(mat * 1024 + n0 + nrow) * 1024 + k0 + cp * 8] = v;
    }
    return;
  }
  {                                      // gq partial sums
    int idx = bx - 3072;                 // 64 blocks
    int kb = idx >> 1, b = idx & 1;
    int col0 = tid * 4;
    float4v s = {0.f, 0.f, 0.f, 0.f};
    for (int k = kb * 32; k < kb * 32 + 32; ++k) {
      float g = ge[b * 1024 + k];
      float4v w = *(const float4v*)&Wgq[(size_t)k * 1024 + col0];
      s.x += g * w.x; s.y += g * w.y; s.z += g * w.z; s.w += g * w.w;
    }
    *(float4v*)&gq_part[(size_t)idx * 1024 + col0] = s;  // [kb*2+b][1024]
  }
}

// ---------------- projection GEMM (m97 structure + dbuf prefetch) ------------
// grid 1025: blocks [0,1024) gemm; block 1024 finishes gq + zeros acc.
__global__ __launch_bounds__(256, 3) void gemm_qkvg(
    const u16* __restrict__ A, const u16* __restrict__ Bw,
    const float* __restrict__ bq, const float* __restrict__ bk,
    const float* __restrict__ bv, const float* __restrict__ bgk,
    const float* __restrict__ bgq, const float* __restrict__ gq_part,
    u16* __restrict__ Qb, u16* __restrict__ Kb,
    u16* __restrict__ GKb, u16* __restrict__ Vt,
    float* __restrict__ gq_final, float* __restrict__ acc3) {
  if (blockIdx.x == 1024) {              // gq finish + acc zero
    int tid = threadIdx.x;
    if (tid < 3) acc3[tid] = 0.f;
#pragma unroll
    for (int i = 0; i < 8; ++i) {
      int t = tid + i * 256;
      float s = bgq[t & 1023];
      for (int kb = 0; kb < 32; ++kb)
        s += gq_part[(size_t)(kb * 2 + (t >> 10)) * 1024 + (t & 1023)];
      gq_final[t] = s;
    }
    return;
  }
  __shared__ __align__(16) u16 As[2][128 * 32];
  __shared__ __align__(16) u16 Bs[2][128 * 32];
  const int tid = threadIdx.x, lane = tid & 63, wv = tid >> 6;
  const int li = lane & 15, quad = lane >> 4;
  const int bid = blockIdx.x;
  const int nb = bid & 31, mb = bid >> 5;
  const u16* Ap = A + (size_t)(mb * 128) * 1024;
  const u16* Bp = Bw + (size_t)(nb * 128) * 1024;
  const int wm0 = (wv >> 1) * 64, wn0 = (wv & 1) * 64;

  f32x4 acc[4][4];
#pragma unroll
  for (int t = 0; t < 4; ++t)
#pragma unroll
    for (int u = 0; u < 4; ++u) acc[t][u] = (f32x4){0.f, 0.f, 0.f, 0.f};

  // prologue: stage kt=0 into buf 0
#pragma unroll
  for (int jj = 0; jj < 2; ++jj) {
    int j = wv * 2 + jj;
    int row = j * 16 + (lane >> 2);
    int co = lane & 3;
    gl_lds16(Ap + (size_t)row * 1024 + co * 8, &As[0][j * 512]);
    gl_lds16(Bp + (size_t)row * 1024 + co * 8, &Bs[0][j * 512]);
  }

  for (int kt = 0; kt < 32; ++kt) {
    const int cur = kt & 1;
    __syncthreads();                     // drains loads for buf cur
    if (kt < 31) {                       // prefetch kt+1 into other buffer
#pragma unroll
      for (int jj = 0; jj < 2; ++jj) {
        int j = wv * 2 + jj;
        int row = j * 16 + (lane >> 2);
        int co = lane & 3;
        gl_lds16(Ap + (size_t)row * 1024 + (kt + 1) * 32 + co * 8, &As[cur ^ 1][j * 512]);
        gl_lds16(Bp + (size_t)row * 1024 + (kt + 1) * 32 + co * 8, &Bs[cur ^ 1][j * 512]);
      }
    }
    bf16x8 af[4], bf[4];
#pragma unroll
    for (int t = 0; t < 4; ++t)
      af[t] = *(const bf16x8*)&As[cur][(wm0 + t * 16 + li) * 32 + quad * 8];
#pragma unroll
    for (int u = 0; u < 4; ++u)
      bf[u] = *(const bf16x8*)&Bs[cur][(wn0 + u * 16 + li) * 32 + quad * 8];
#pragma unroll
    for (int t = 0; t < 4; ++t)
#pragma unroll
      for (int u = 0; u < 4; ++u)
        acc[t][u] = __builtin_amdgcn_mfma_f32_16x16x32_bf16(af[t], bf[u], acc[t][u], 0, 0, 0);
  }

  const int nbase = nb * 128;
  const int mat = nbase >> 10;           // block never straddles matrices
  if (mat == 2) {
    // V: write transposed Vt[b][col][s] directly, 4 consecutive s per b64
#pragma unroll
    for (int t = 0; t < 4; ++t)
#pragma unroll
      for (int u = 0; u < 4; ++u) {
        int col = (nbase & 1023) + wn0 + u * 16 + li;
        float bb = bv[col];
        int row = mb * 128 + wm0 + t * 16 + quad * 4;  // r=0 row
        int b = row >> 11, s = row & 2047;
        uint2 w;
        w.x = pk2(acc[t][u][1] + bb, acc[t][u][0] + bb);
        w.y = pk2(acc[t][u][3] + bb, acc[t][u][2] + bb);
        *(uint2*)&Vt[(size_t)b * (1024 * 2048) + (size_t)col * 2048 + s] = w;
      }
  } else {
    const float* bias = (mat == 0) ? bq : (mat == 1) ? bk : bgk;
    u16* outp = (mat == 0) ? Qb : (mat == 1) ? Kb : GKb;
    // Q pre-scaled by 1/sqrt(64) * log2(e) for exp2-based softmax
    const float qscale = (mat == 0) ? 0.18033688f : 1.0f;
#pragma unroll
    for (int t = 0; t < 4; ++t)
#pragma unroll
      for (int u = 0; u < 4; ++u) {
        int col = (nbase & 1023) + wn0 + u * 16 + li;
        float bb = bias[col];
#pragma unroll
        for (int r = 0; r < 4; ++r) {
          int row = mb * 128 + wm0 + t * 16 + quad * 4 + r;
          outp[(size_t)row * 1024 + col] = f2bf((acc[t][u][r] + bb) * qscale);
        }
      }
  }
}

// ---------------- flash attention: 32x32 MFMA, 64 queries/wave --------------
// grid 256 x 256. bh = bx&31 (XCD-L2 locality), qb = bx>>5 in [0,8).
__global__ __launch_bounds__(256, 2) void attn_kernel(
    const u16* __restrict__ Qb, const u16* __restrict__ Kb,
    const u16* __restrict__ Vt, float* __restrict__ out,
    float* __restrict__ acc3 /*[0]=ent,[1]=conc*/) {
  __shared__ __align__(16) u16 Ks[2][128 * 64];   // [key][k], swizzled chunks
  __shared__ __align__(16) u16 Vs[2][64 * 128];   // [d][key], swizzled chunks
  __shared__ float red[8];

  const int tid = threadIdx.x, lane = tid & 63, wv = tid >> 6;
  const int q_l = lane & 31, half = lane >> 5;
  const int bx = blockIdx.x;
  const int bh = bx & 31, qb = bx >> 5;
  const int b = bh >> 4, h = bh & 15;
  const int qrow0 = qb * 256 + wv * 64;   // + qt*32 + q_l

  const u16* Qp = Qb + (size_t)(b * 2048 + qrow0 + q_l) * 1024 + h * 64;
  const u16* Kp = Kb + (size_t)(b * 2048) * 1024 + h * 64;
  const u16* Vp = Vt + (size_t)b * (1024 * 2048) + (size_t)(h * 64) * 2048;

  // Q^T B-frags in registers: lane (q=q_l, half) holds k = s*16 + half*8 + j
  bf16x8 qf[2][4];
#pragma unroll
  for (int qt = 0; qt < 2; ++qt)
#pragma unroll
    for (int s = 0; s < 4; ++s)
      qf[qt][s] = *(const bf16x8*)&Qp[(size_t)qt * 32 * 1024 + s * 16 + half * 8];

  float m_st[2] = {-3.0e38f, -3.0e38f}, l_st[2] = {0.f, 0.f}, e_st[2] = {0.f, 0.f};
  f32x16 accO[2][2];  // [qt][dt]: O^T rows d = dt*32 + (reg&3)+8*(reg>>2)+4*half
#pragma unroll
  for (int qt = 0; qt < 2; ++qt)
#pragma unroll
    for (int dt = 0; dt < 2; ++dt)
#pragma unroll
      for (int r = 0; r < 16; ++r) accO[qt][dt][r] = 0.f;

  // prologue: stage tile 0 into buf 0 (K: 16 KB, V: 16 KB; 4 issues/wave each)
#pragma unroll
  for (int jj = 0; jj < 4; ++jj) {
    int j = wv * 4 + jj;
    int row = j * 8 + (lane >> 3);
    int c16 = (lane & 7) ^ (row & 7);
    gl_lds16(Kp + (size_t)row * 1024 + c16 * 8, &Ks[0][j * 512]);
  }
#pragma unroll
  for (int jj = 0; jj < 4; ++jj) {
    int j = wv * 4 + jj;
    int row = j * 4 + (lane >> 4);
    int c16 = (lane & 15) ^ (row & 7);
    gl_lds16(Vp + (size_t)row * 2048 + c16 * 8, &Vs[0][j * 512]);
  }

  for (int kt = 0; kt < 16; ++kt) {
    const int cur = kt & 1;
    __syncthreads();                     // drains tile-kt loads
    if (kt < 15) {                       // prefetch kt+1; compute hides it
      const u16* Kpt = Kp + (size_t)((kt + 1) * 128) * 1024;
#pragma unroll
      for (int jj = 0; jj < 4; ++jj) {
        int j = wv * 4 + jj;
        int row = j * 8 + (lane >> 3);
        int c16 = (lane & 7) ^ (row & 7);
        gl_lds16(Kpt + (size_t)row * 1024 + c16 * 8, &Ks[cur ^ 1][j * 512]);
      }
#pragma unroll
      for (int jj = 0; jj < 4; ++jj) {
        int j = wv * 4 + jj;
        int row = j * 4 + (lane >> 4);
        int c16 = (lane & 15) ^ (row & 7);
        gl_lds16(Vp + (size_t)row * 2048 + (kt + 1) * 128 + c16 * 8, &Vs[cur ^ 1][j * 512]);
      }
    }
    const u16* KsC = &Ks[cur][0];
    const u16* VsC = &Vs[cur][0];

#pragma unroll
    for (int u = 0; u < 4; ++u) {        // 32-key tiles
      // K A-frags (shared across qt): m=key=u*32+q_l, k = s*16+half*8+j
      bf16x8 ka[4];
#pragma unroll
      for (int s = 0; s < 4; ++s)
        ka[s] = *(const bf16x8*)&KsC[(u * 32 + q_l) * 64 + (((2 * s + half) ^ (q_l & 7))) * 8];
      // V A-frags (shared across qt): m=d, k=key
      bf16x8 av[2][2];
#pragma unroll
      for (int dt = 0; dt < 2; ++dt) {
        int d = dt * 32 + q_l;
#pragma unroll
        for (int kc = 0; kc < 2; ++kc)
          av[dt][kc] = *(const bf16x8*)&VsC[d * 128 + ((u * 4 + kc * 2 + half) ^ (d & 7)) * 8];
      }
#pragma unroll
      for (int qt = 0; qt < 2; ++qt) {
        f32x16 c;
#pragma unroll
        for (int r = 0; r < 16; ++r) c[r] = 0.f;
#pragma unroll
        for (int s = 0; s < 4; ++s)
          c = __builtin_amdgcn_mfma_f32_32x32x16_bf16(ka[s], qf[qt][s], c, 0, 0, 0);
        // no-max softmax stats + exp (native v_exp_f32), in-register
        float cmx = m_st[qt], ps = 0.f, es = 0.f;
#pragma unroll
        for (int r = 0; r < 16; ++r) {
          float sv = c[r];
          cmx = fmaxf(cmx, sv);
          float pe = EXP2(sv);
          ps += pe;
          es = __builtin_fmaf(pe, sv, es);
          c[r] = pe;
        }
        m_st[qt] = cmx;
        l_st[qt] += ps;
        e_st[qt] += es;
        // pack P pairs then permlane32_swap into PV B-operand layout
        unsigned p0 = pk2(c[1], c[0]),   p1 = pk2(c[3], c[2]);
        unsigned p2 = pk2(c[5], c[4]),   p3 = pk2(c[7], c[6]);
        unsigned p4 = pk2(c[9], c[8]),   p5 = pk2(c[11], c[10]);
        unsigned p6 = pk2(c[13], c[12]), p7 = pk2(c[15], c[14]);
        plswap(p0, p2, lane); plswap(p1, p3, lane);   // keys u*32 + 0..15
        plswap(p4, p6, lane); plswap(p5, p7, lane);   // keys u*32 + 16..31
        bf16x8 bf0 = mk8(p0, p1, p2, p3);
        bf16x8 bf1 = mk8(p4, p5, p6, p7);
#pragma unroll
        for (int dt = 0; dt < 2; ++dt) {
          accO[qt][dt] = __builtin_amdgcn_mfma_f32_32x32x16_bf16(av[dt][0], bf0, accO[qt][dt], 0, 0, 0);
          accO[qt][dt] = __builtin_amdgcn_mfma_f32_32x32x16_bf16(av[dt][1], bf1, accO[qt][dt], 0, 0, 0);
        }
      }
    }
  }

  // epilogue: lane owns query q_l (dup across half); reduce half, write, stats
  float entw = 0.f, concw = 0.f;
#pragma unroll
  for (int qt = 0; qt < 2; ++qt) {
    float lsum = l_st[qt] + __shfl_xor(l_st[qt], 32, 64);
    float esum = e_st[qt] + __shfl_xor(e_st[qt], 32, 64);
    float mm = fmaxf(m_st[qt], __shfl_xor(m_st[qt], 32, 64));
    float inv = 1.0f / lsum;
    entw += __logf(lsum) - 0.69314718f * esum * inv;  // s' in log2 units
    concw += exp2f(mm) * inv;
    float* outp = out + (size_t)(b * 2048 + qrow0 + qt * 32 + q_l) * 1024 + h * 64;
#pragma unroll
    for (int dt = 0; dt < 2; ++dt)
#pragma unroll
      for (int g = 0; g < 4; ++g) {
        float4v o;
        o.x = accO[qt][dt][4 * g + 0] * inv; o.y = accO[qt][dt][4 * g + 1] * inv;
        o.z = accO[qt][dt][4 * g + 2] * inv; o.w = accO[qt][dt][4 * g + 3] * inv;
        *(float4v*)&outp[dt * 32 + 8 * g + 4 * half] = o;
      }
  }
#pragma unroll
  for (int off = 1; off < 64; off <<= 1) {
    entw += __shfl_xor(entw, off, 64);
    concw += __shfl_xor(concw, off, 64);
  }
  if (lane == 0) { red[wv] = entw * 0.5f; red[4 + wv] = concw * 0.5f; }  // /2 dup
  __syncthreads();
  if (tid == 0) {
    atomicAdd(&acc3[0], red[0] + red[1] + red[2] + red[3]);
    atomicAdd(&acc3[1], red[4] + red[5] + red[6] + red[7]);
  }
}

// ---------------- influence: sum |gq . gk| over (b,h,s) ----------------
__global__ void gov_kernel(const u16* __restrict__ GKb, const float* __restrict__ gq,
                           float* __restrict__ acc_inf) {
  __shared__ float redI[4];
  int lane = threadIdx.x & 63, wv = threadIdx.x >> 6;
  int wid = blockIdx.x * 4 + wv;          // one wave per (b,s)
  int b = wid >> 11, s = wid & 2047;
  const u16* gk = GKb + (size_t)(b * 2048 + s) * 1024 + lane * 16;
  const float* gqp = gq + b * 1024 + lane * 16;
  bf16x8 g0 = *(const bf16x8*)gk, g1 = *(const bf16x8*)(gk + 8);
  float4v q0 = *(const float4v*)&gqp[0], q1 = *(const float4v*)&gqp[4];
  float4v q2 = *(const float4v*)&gqp[8], q3 = *(const float4v*)&gqp[12];
  float sum = 0.f;
  sum += bf2f((u16)g0[0]) * q0.x + bf2f((u16)g0[1]) * q0.y +
         bf2f((u16)g0[2]) * q0.z + bf2f((u16)g0[3]) * q0.w;
  sum += bf2f((u16)g0[4]) * q1.x + bf2f((u16)g0[5]) * q1.y +
         bf2f((u16)g0[6]) * q1.z + bf2f((u16)g0[7]) * q1.w;
  sum += bf2f((u16)g1[0]) * q2.x + bf2f((u16)g1[1]) * q2.y +
         bf2f((u16)g1[2]) * q2.z + bf2f((u16)g1[3]) * q2.w;
  sum += bf2f((u16)g1[4]) * q3.x + bf2f((u16)g1[5]) * q3.y +
         bf2f((u16)g1[6]) * q3.z + bf2f((u16)g1[7]) * q3.w;
  sum += __shfl_xor(sum, 1, 64);
  sum += __shfl_xor(sum, 2, 64);
  float v = ((lane & 3) == 0) ? fabsf(sum) : 0.f;
  v += __shfl_xor(v, 4, 64);  v += __shfl_xor(v, 8, 64);
  v += __shfl_xor(v, 16, 64); v += __shfl_xor(v, 32, 64);
  if (lane == 0) redI[wv] = v;
  __syncthreads();
  if (threadIdx.x == 0)
    atomicAdd(acc_inf, redI[0] + redI[1] + redI[2] + redI[3]);
}

__global__ void finalize(const float* __restrict__ acc3, float* __restrict__ out) {
  if (threadIdx.x == 0) {
    out[0] = acc3[0] * (1.f / 65536.f);  // entropy
    out[1] = acc3[2] * (1.f / 65536.f);  // influence
    out[2] = acc3[1] * (1.f / 65536.f);  // concentration
  }
}

extern "C" void kernel_launch(void* const* d_in, const int* in_sizes, int n_in,
                              void* d_out, int out_size, void* d_ws, size_t ws_size,
                              hipStream_t stream) {
  (void)in_sizes; (void)n_in; (void)out_size; (void)ws_size;
  const float* hs  = (const float*)d_in[0];
  const float* ge  = (const float*)d_in[1];
  const float* Wq  = (const float*)d_in[2];
  const float* bq  = (const float*)d_in[3];
  const float* Wk  = (const float*)d_in[4];
  const float* bk  = (const float*)d_in[5];
  const float* Wv  = (const float*)d_in[6];
  const float* bv  = (const float*)d_in[7];
  const float* Wgq = (const float*)d_in[8];
  const float* bgq = (const float*)d_in[9];
  const float* Wgk = (const float*)d_in[10];
  const float* bgk = (const float*)d_in[11];

  char* ws = (char*)d_ws;
  u16* hsB = (u16*)(ws);
  u16* WB  = (u16*)(ws + (size_t)(8 << 20));
  u16* Qb  = (u16*)(ws + (size_t)(16 << 20));
  u16* Kb  = (u16*)(ws + (size_t)(24 << 20));
  u16* Vt  = (u16*)(ws + (size_t)(32 << 20));
  u16* GKb = (u16*)(ws + (size_t)(40 << 20));
  float* gq_part  = (float*)(ws + (size_t)(48 << 20));           // 256 KB
  float* gq_final = (float*)(ws + (size_t)(48 << 20) + 262144);  // 8 KB
  float* acc3     = (float*)(ws + (size_t)(48 << 20) + 524288);
  float* out = (float*)d_out;

  prep<<<3136, 256, 0, stream>>>(hs, Wq, Wk, Wv, Wgk, ge, Wgq, hsB, WB, gq_part);
  gemm_qkvg<<<1025, 256, 0, stream>>>(hsB, WB, bq, bk, bv, bgk, bgq, gq_part,
                                      Qb, Kb, GKb, Vt, gq_final, acc3);
  attn_kernel<<<256, 256, 0, stream>>>(Qb, Kb, Vt, out, acc3);
  gov_kernel<<<1024, 256, 0, stream>>>(GKb, gq_final, acc3 + 2);
  finalize<<<1, 64, 0, stream>>>(acc3, out + 4194304);
}

// Round 6
// 222.466 us; speedup vs baseline: 1.3161x; 1.3161x over previous
//
#include <hip/hip_runtime.h>

// GovernanceAwareAttention on MI355X (gfx950). Round 6.
// Governance bias is constant along key axis -> softmax invariant -> only
// `influence` needs gov_scores. bf16 MFMA projections + flash attention.
//
// R6: revert attention to R4's 32-queries/wave (R5's 64 q/wave spilled to
// scratch: VGPR 88->128+AGPR, WRITE_SIZE 16->176 MB). Keep native v_exp_f32
// (libm exp2f = OCML sequence was the VALUBusy=57% consumer), add f32x2
// packed softmax stats (v_pk_max/add/fma halve stat insts), keep gemm dbuf.

typedef unsigned short u16;
typedef __attribute__((ext_vector_type(8))) short bf16x8;   // 8 bf16 = 4 VGPR
typedef __attribute__((ext_vector_type(4))) float f32x4;
typedef __attribute__((ext_vector_type(16))) float f32x16;
typedef __attribute__((ext_vector_type(2))) float f32x2;
typedef __attribute__((ext_vector_type(4))) u16 u16x4;
typedef __attribute__((ext_vector_type(4))) float float4v;
typedef __attribute__((ext_vector_type(2))) unsigned uint2v;

typedef const __attribute__((address_space(1))) void gvoid_t;
typedef __attribute__((address_space(3))) void lvoid_t;

__device__ __forceinline__ void gl_lds16(const void* g, void* l) {
  // async global->LDS, 16B/lane; LDS dest is wave-uniform base + lane*16
  __builtin_amdgcn_global_load_lds((gvoid_t*)g, (lvoid_t*)l, 16, 0, 0);
}

__device__ __forceinline__ u16 f2bf(float x) {  // RNE f32->bf16
  union { float f; unsigned u; } v; v.f = x;
  unsigned r = v.u + 0x7fffu + ((v.u >> 16) & 1u);
  return (u16)(r >> 16);
}
__device__ __forceinline__ float bf2f(u16 h) {
  union { unsigned u; float f; } v; v.u = ((unsigned)h) << 16; return v.f;
}
// pack two f32 -> two truncated bf16 in one v_perm_b32 (lo in low half)
__device__ __forceinline__ unsigned pk2(float hi, float lo) {
  union { float f; unsigned u; } a, b; a.f = hi; b.f = lo;
  return __builtin_amdgcn_perm(a.u, b.u, 0x07060302u);
}
__device__ __forceinline__ bf16x8 mk8(unsigned a, unsigned b, unsigned c, unsigned d) {
  union { unsigned u[4]; bf16x8 v; } x;
  x.u[0] = a; x.u[1] = b; x.u[2] = c; x.u[3] = d; return x.v;
}

#if defined(__has_builtin)
#if __has_builtin(__builtin_amdgcn_permlane32_swap)
#define HAVE_PLSWAP 1
#endif
#if __has_builtin(__builtin_amdgcn_exp2f)
#define EXP2(x) __builtin_amdgcn_exp2f(x)
#endif
#endif
#ifndef EXP2
#define EXP2(x) exp2f(x)
#endif

// a' = {a.lo, b.lo}, b' = {a.hi, b.hi}  (swap a's upper 32 lanes w/ b's lower)
__device__ __forceinline__ void plswap(unsigned& a, unsigned& b, int lane) {
#ifdef HAVE_PLSWAP
  uint2v r = __builtin_amdgcn_permlane32_swap(a, b, false, false);
  a = r.x; b = r.y;
#else
  unsigned ca = __builtin_amdgcn_ds_bpermute((lane ^ 32) << 2, a);
  unsigned cb = __builtin_amdgcn_ds_bpermute((lane ^ 32) << 2, b);
  unsigned na = (lane < 32) ? a : cb;
  unsigned nb = (lane < 32) ? ca : b;
  a = na; b = nb;
#endif
}

// ---------------- prep: hs->bf16, W->W^T bf16, gq partials ----------------
// grid 3136: [0,2048) conv_hs, [2048,3072) conv_w, [3072,3136) gq partials.
__global__ void prep(const float* __restrict__ hs,
                     const float* __restrict__ W0, const float* __restrict__ W1,
                     const float* __restrict__ W2, const float* __restrict__ W3,
                     const float* __restrict__ ge, const float* __restrict__ Wgq,
                     u16* __restrict__ hsB, u16* __restrict__ WB,
                     float* __restrict__ gq_part) {
  __shared__ __align__(16) u16 T[64][72];
  int bx = blockIdx.x, tid = threadIdx.x;
  if (bx < 2048) {                       // hs f32 [4096x1024] -> bf16, RNE
    int i = bx * 256 + tid;
    const float4v* in4 = (const float4v*)hs;
    float4v a = in4[i * 2], b = in4[i * 2 + 1];
    bf16x8 v;
    v[0] = (short)f2bf(a.x); v[1] = (short)f2bf(a.y);
    v[2] = (short)f2bf(a.z); v[3] = (short)f2bf(a.w);
    v[4] = (short)f2bf(b.x); v[5] = (short)f2bf(b.y);
    v[6] = (short)f2bf(b.z); v[7] = (short)f2bf(b.w);
    *(bf16x8*)&hsB[(size_t)i * 8] = v;
    return;
  }
  if (bx < 3072) {                       // W[k][n] -> WB[mat*1024+n][k], LDS xpose
    int idx = bx - 2048;
    int mat = idx >> 8, sub = idx & 255;
    const float* W = (mat == 0) ? W0 : (mat == 1) ? W1 : (mat == 2) ? W2 : W3;
    int k0 = (sub >> 4) * 64, n0 = (sub & 15) * 64;
#pragma unroll
    for (int p = 0; p < 4; ++p) {
      int chunk = p * 256 + tid;
      int row = chunk >> 4, cp = chunk & 15;
      float4v v = *(const float4v*)&W[(size_t)(k0 + row) * 1024 + n0 + cp * 4];
      u16x4 o; o.x = f2bf(v.x); o.y = f2bf(v.y); o.z = f2bf(v.z); o.w = f2bf(v.w);
      *(u16x4*)&T[row][cp * 4] = o;
    }
    __syncthreads();
#pragma unroll
    for (int p = 0; p < 2; ++p) {
      int chunk = p * 256 + tid;
      int nrow = chunk >> 3, cp = chunk & 7;
      bf16x8 v;
#pragma unroll
      for (int e = 0; e < 8; ++e) v[e] = (short)T[cp * 8 + e][nrow];
      *(bf16x8*)&WB[(size_t)(mat * 1024 + n0 + nrow) * 1024 + k0 + cp * 8] = v;
    }
    return;
  }
  {                                      // gq partial sums
    int idx = bx - 3072;                 // 64 blocks
    int kb = idx >> 1, b = idx & 1;
    int col0 = tid * 4;
    float4v s = {0.f, 0.f, 0.f, 0.f};
    for (int k = kb * 32; k < kb * 32 + 32; ++k) {
      float g = ge[b * 1024 + k];
      float4v w = *(const float4v*)&Wgq[(size_t)k * 1024 + col0];
      s.x += g * w.x; s.y += g * w.y; s.z += g * w.z; s.w += g * w.w;
    }
    *(float4v*)&gq_part[(size_t)idx * 1024 + col0] = s;  // [kb*2+b][1024]
  }
}

// ---------------- projection GEMM (m97 structure + dbuf prefetch) ------------
// grid 1025: blocks [0,1024) gemm; block 1024 finishes gq + zeros acc.
__global__ __launch_bounds__(256, 3) void gemm_qkvg(
    const u16* __restrict__ A, const u16* __restrict__ Bw,
    const float* __restrict__ bq, const float* __restrict__ bk,
    const float* __restrict__ bv, const float* __restrict__ bgk,
    const float* __restrict__ bgq, const float* __restrict__ gq_part,
    u16* __restrict__ Qb, u16* __restrict__ Kb,
    u16* __restrict__ GKb, u16* __restrict__ Vt,
    float* __restrict__ gq_final, float* __restrict__ acc3) {
  if (blockIdx.x == 1024) {              // gq finish + acc zero
    int tid = threadIdx.x;
    if (tid < 3) acc3[tid] = 0.f;
#pragma unroll
    for (int i = 0; i < 8; ++i) {
      int t = tid + i * 256;
      float s = bgq[t & 1023];
      for (int kb = 0; kb < 32; ++kb)
        s += gq_part[(size_t)(kb * 2 + (t >> 10)) * 1024 + (t & 1023)];
      gq_final[t] = s;
    }
    return;
  }
  __shared__ __align__(16) u16 As[2][128 * 32];
  __shared__ __align__(16) u16 Bs[2][128 * 32];
  const int tid = threadIdx.x, lane = tid & 63, wv = tid >> 6;
  const int li = lane & 15, quad = lane >> 4;
  const int bid = blockIdx.x;
  const int nb = bid & 31, mb = bid >> 5;
  const u16* Ap = A + (size_t)(mb * 128) * 1024;
  const u16* Bp = Bw + (size_t)(nb * 128) * 1024;
  const int wm0 = (wv >> 1) * 64, wn0 = (wv & 1) * 64;

  f32x4 acc[4][4];
#pragma unroll
  for (int t = 0; t < 4; ++t)
#pragma unroll
    for (int u = 0; u < 4; ++u) acc[t][u] = (f32x4){0.f, 0.f, 0.f, 0.f};

  // prologue: stage kt=0 into buf 0
#pragma unroll
  for (int jj = 0; jj < 2; ++jj) {
    int j = wv * 2 + jj;
    int row = j * 16 + (lane >> 2);
    int co = lane & 3;
    gl_lds16(Ap + (size_t)row * 1024 + co * 8, &As[0][j * 512]);
    gl_lds16(Bp + (size_t)row * 1024 + co * 8, &Bs[0][j * 512]);
  }

  for (int kt = 0; kt < 32; ++kt) {
    const int cur = kt & 1;
    __syncthreads();                     // drains loads for buf cur
    if (kt < 31) {                       // prefetch kt+1 into other buffer
#pragma unroll
      for (int jj = 0; jj < 2; ++jj) {
        int j = wv * 2 + jj;
        int row = j * 16 + (lane >> 2);
        int co = lane & 3;
        gl_lds16(Ap + (size_t)row * 1024 + (kt + 1) * 32 + co * 8, &As[cur ^ 1][j * 512]);
        gl_lds16(Bp + (size_t)row * 1024 + (kt + 1) * 32 + co * 8, &Bs[cur ^ 1][j * 512]);
      }
    }
    bf16x8 af[4], bf[4];
#pragma unroll
    for (int t = 0; t < 4; ++t)
      af[t] = *(const bf16x8*)&As[cur][(wm0 + t * 16 + li) * 32 + quad * 8];
#pragma unroll
    for (int u = 0; u < 4; ++u)
      bf[u] = *(const bf16x8*)&Bs[cur][(wn0 + u * 16 + li) * 32 + quad * 8];
#pragma unroll
    for (int t = 0; t < 4; ++t)
#pragma unroll
      for (int u = 0; u < 4; ++u)
        acc[t][u] = __builtin_amdgcn_mfma_f32_16x16x32_bf16(af[t], bf[u], acc[t][u], 0, 0, 0);
  }

  const int nbase = nb * 128;
  const int mat = nbase >> 10;           // block never straddles matrices
  if (mat == 2) {
    // V: write transposed Vt[b][col][s] directly, 4 consecutive s per b64
#pragma unroll
    for (int t = 0; t < 4; ++t)
#pragma unroll
      for (int u = 0; u < 4; ++u) {
        int col = (nbase & 1023) + wn0 + u * 16 + li;
        float bb = bv[col];
        int row = mb * 128 + wm0 + t * 16 + quad * 4;  // r=0 row
        int b = row >> 11, s = row & 2047;
        uint2 w;
        w.x = pk2(acc[t][u][1] + bb, acc[t][u][0] + bb);
        w.y = pk2(acc[t][u][3] + bb, acc[t][u][2] + bb);
        *(uint2*)&Vt[(size_t)b * (1024 * 2048) + (size_t)col * 2048 + s] = w;
      }
  } else {
    const float* bias = (mat == 0) ? bq : (mat == 1) ? bk : bgk;
    u16* outp = (mat == 0) ? Qb : (mat == 1) ? Kb : GKb;
    // Q pre-scaled by 1/sqrt(64) * log2(e) for exp2-based softmax
    const float qscale = (mat == 0) ? 0.18033688f : 1.0f;
#pragma unroll
    for (int t = 0; t < 4; ++t)
#pragma unroll
      for (int u = 0; u < 4; ++u) {
        int col = (nbase & 1023) + wn0 + u * 16 + li;
        float bb = bias[col];
#pragma unroll
        for (int r = 0; r < 4; ++r) {
          int row = mb * 128 + wm0 + t * 16 + quad * 4 + r;
          outp[(size_t)row * 1024 + col] = f2bf((acc[t][u][r] + bb) * qscale);
        }
      }
  }
}

// ---------------- flash attention: 32x32 MFMA, register P transform ----------
// grid 512 x 256. bh = bx&31 (XCD-L2 locality), qb = bx>>5.
__global__ __launch_bounds__(256, 2) void attn_kernel(
    const u16* __restrict__ Qb, const u16* __restrict__ Kb,
    const u16* __restrict__ Vt, float* __restrict__ out,
    float* __restrict__ acc3 /*[0]=ent,[1]=conc*/) {
  __shared__ __align__(16) u16 Ks[2][128 * 64];   // [key][k], swizzled chunks
  __shared__ __align__(16) u16 Vs[2][64 * 128];   // [d][key], swizzled chunks
  __shared__ float red[8];

  const int tid = threadIdx.x, lane = tid & 63, wv = tid >> 6;
  const int q_l = lane & 31, half = lane >> 5;
  const int bx = blockIdx.x;
  const int bh = bx & 31, qb = bx >> 5;
  const int b = bh >> 4, h = bh & 15;

  const u16* Qp = Qb + (size_t)(b * 2048 + qb * 128 + wv * 32 + q_l) * 1024 + h * 64;
  const u16* Kp = Kb + (size_t)(b * 2048) * 1024 + h * 64;
  const u16* Vp = Vt + (size_t)b * (1024 * 2048) + (size_t)(h * 64) * 2048;

  // Q^T B-frags in registers: lane (q=q_l, half) holds k = s*16 + half*8 + j
  // (already scaled by 0.125*log2e in gemm)
  bf16x8 qf[4];
#pragma unroll
  for (int s = 0; s < 4; ++s)
    qf[s] = *(const bf16x8*)&Qp[s * 16 + half * 8];

  f32x2 mx2 = {-3.0e38f, -3.0e38f}, ps2 = {0.f, 0.f}, es2 = {0.f, 0.f};
  f32x16 accO[2];   // O^T: rows d = dt*32 + (reg&3)+8*(reg>>2)+4*half, col q
#pragma unroll
  for (int dt = 0; dt < 2; ++dt)
#pragma unroll
    for (int r = 0; r < 16; ++r) accO[dt][r] = 0.f;

  // prologue: stage tile 0 into buf 0
#pragma unroll
  for (int jj = 0; jj < 4; ++jj) {
    int j = wv * 4 + jj;
    int row = j * 8 + (lane >> 3);
    int c16 = (lane & 7) ^ (row & 7);
    gl_lds16(Kp + (size_t)row * 1024 + c16 * 8, &Ks[0][j * 512]);
  }
#pragma unroll
  for (int jj = 0; jj < 4; ++jj) {
    int j = wv * 4 + jj;
    int row = j * 4 + (lane >> 4);
    int c16 = (lane & 15) ^ (row & 7);
    gl_lds16(Vp + (size_t)row * 2048 + c16 * 8, &Vs[0][j * 512]);
  }

  for (int kt = 0; kt < 16; ++kt) {
    const int cur = kt & 1;
    __syncthreads();                     // drains tile-kt loads
    if (kt < 15) {                       // prefetch kt+1; compute hides it
      const u16* Kpt = Kp + (size_t)((kt + 1) * 128) * 1024;
#pragma unroll
      for (int jj = 0; jj < 4; ++jj) {
        int j = wv * 4 + jj;
        int row = j * 8 + (lane >> 3);
        int c16 = (lane & 7) ^ (row & 7);
        gl_lds16(Kpt + (size_t)row * 1024 + c16 * 8, &Ks[cur ^ 1][j * 512]);
      }
#pragma unroll
      for (int jj = 0; jj < 4; ++jj) {
        int j = wv * 4 + jj;
        int row = j * 4 + (lane >> 4);
        int c16 = (lane & 15) ^ (row & 7);
        gl_lds16(Vp + (size_t)row * 2048 + (kt + 1) * 128 + c16 * 8, &Vs[cur ^ 1][j * 512]);
      }
    }
    const u16* KsC = &Ks[cur][0];
    const u16* VsC = &Vs[cur][0];

#pragma unroll
    for (int u = 0; u < 4; ++u) {        // 32-key tiles
      // S^T tile = K * Q^T  (A = K-frag: m=key, k = s*16+half*8+j)
      f32x16 c;
#pragma unroll
      for (int r = 0; r < 16; ++r) c[r] = 0.f;
#pragma unroll
      for (int s = 0; s < 4; ++s) {
        int p = (2 * s + half) ^ (q_l & 7);       // key row = u*32+q_l
        bf16x8 a = *(const bf16x8*)&KsC[(u * 32 + q_l) * 64 + p * 8];
        c = __builtin_amdgcn_mfma_f32_32x32x16_bf16(a, qf[s], c, 0, 0, 0);
      }
      // no-max softmax stats (packed f32x2) + native v_exp_f32
#pragma unroll
      for (int r = 0; r < 8; ++r) {
        f32x2 sv = {c[2 * r], c[2 * r + 1]};
        mx2 = __builtin_elementwise_max(mx2, sv);
        f32x2 pe = {EXP2(sv.x), EXP2(sv.y)};
        ps2 += pe;
        es2 += pe * sv;                  // v_pk_fma_f32
        c[2 * r] = pe.x; c[2 * r + 1] = pe.y;
      }
      // pack P pairs (consecutive keys share a b32) then permlane32_swap
      // into PV B-operand layout: reg j holds keys half*8+2j, +1
      unsigned p0 = pk2(c[1], c[0]),   p1 = pk2(c[3], c[2]);
      unsigned p2 = pk2(c[5], c[4]),   p3 = pk2(c[7], c[6]);
      unsigned p4 = pk2(c[9], c[8]),   p5 = pk2(c[11], c[10]);
      unsigned p6 = pk2(c[13], c[12]), p7 = pk2(c[15], c[14]);
      plswap(p0, p2, lane); plswap(p1, p3, lane);   // keys u*32 + 0..15
      plswap(p4, p6, lane); plswap(p5, p7, lane);   // keys u*32 + 16..31
      bf16x8 bf0 = mk8(p0, p1, p2, p3);
      bf16x8 bf1 = mk8(p4, p5, p6, p7);
      // PV: O^T += V^T * P^T  (A = V-frag: m=d, k=key)
#pragma unroll
      for (int dt = 0; dt < 2; ++dt) {
        int d = dt * 32 + q_l;
        int pa = (u * 4 + half) ^ (d & 7);
        int pb = (u * 4 + 2 + half) ^ (d & 7);
        bf16x8 av0 = *(const bf16x8*)&VsC[d * 128 + pa * 8];
        accO[dt] = __builtin_amdgcn_mfma_f32_32x32x16_bf16(av0, bf0, accO[dt], 0, 0, 0);
        bf16x8 av1 = *(const bf16x8*)&VsC[d * 128 + pb * 8];
        accO[dt] = __builtin_amdgcn_mfma_f32_32x32x16_bf16(av1, bf1, accO[dt], 0, 0, 0);
      }
    }
  }

  // epilogue: each lane owns query q_l (duplicated across half)
  float l_st = ps2.x + ps2.y, e_st = es2.x + es2.y, m_st = fmaxf(mx2.x, mx2.y);
  float lsum = l_st + __shfl_xor(l_st, 32, 64);
  float esum = e_st + __shfl_xor(e_st, 32, 64);
  float mm = fmaxf(m_st, __shfl_xor(m_st, 32, 64));
  float inv = 1.0f / lsum;
  float entw = __logf(lsum) - 0.69314718f * esum * inv;  // s' in log2 units
  float concw = EXP2(mm) * inv;

  float* outp = out + (size_t)(b * 2048 + qb * 128 + wv * 32 + q_l) * 1024 + h * 64;
#pragma unroll
  for (int dt = 0; dt < 2; ++dt)
#pragma unroll
    for (int g = 0; g < 4; ++g) {
      float4v o;
      o.x = accO[dt][4 * g + 0] * inv; o.y = accO[dt][4 * g + 1] * inv;
      o.z = accO[dt][4 * g + 2] * inv; o.w = accO[dt][4 * g + 3] * inv;
      *(float4v*)&outp[dt * 32 + 8 * g + 4 * half] = o;
    }

#pragma unroll
  for (int off = 1; off < 64; off <<= 1) {
    entw += __shfl_xor(entw, off, 64);
    concw += __shfl_xor(concw, off, 64);
  }
  if (lane == 0) { red[wv] = entw * 0.5f; red[4 + wv] = concw * 0.5f; }  // /2 dup
  __syncthreads();
  if (tid == 0) {
    atomicAdd(&acc3[0], red[0] + red[1] + red[2] + red[3]);
    atomicAdd(&acc3[1], red[4] + red[5] + red[6] + red[7]);
  }
}

// ---------------- influence: sum |gq . gk| over (b,h,s) ----------------
__global__ void gov_kernel(const u16* __restrict__ GKb, const float* __restrict__ gq,
                           float* __restrict__ acc_inf) {
  __shared__ float redI[4];
  int lane = threadIdx.x & 63, wv = threadIdx.x >> 6;
  int wid = blockIdx.x * 4 + wv;          // one wave per (b,s)
  int b = wid >> 11, s = wid & 2047;
  const u16* gk = GKb + (size_t)(b * 2048 + s) * 1024 + lane * 16;
  const float* gqp = gq + b * 1024 + lane * 16;
  bf16x8 g0 = *(const bf16x8*)gk, g1 = *(const bf16x8*)(gk + 8);
  float4v q0 = *(const float4v*)&gqp[0], q1 = *(const float4v*)&gqp[4];
  float4v q2 = *(const float4v*)&gqp[8], q3 = *(const float4v*)&gqp[12];
  float sum = 0.f;
  sum += bf2f((u16)g0[0]) * q0.x + bf2f((u16)g0[1]) * q0.y +
         bf2f((u16)g0[2]) * q0.z + bf2f((u16)g0[3]) * q0.w;
  sum += bf2f((u16)g0[4]) * q1.x + bf2f((u16)g0[5]) * q1.y +
         bf2f((u16)g0[6]) * q1.z + bf2f((u16)g0[7]) * q1.w;
  sum += bf2f((u16)g1[0]) * q2.x + bf2f((u16)g1[1]) * q2.y +
         bf2f((u16)g1[2]) * q2.z + bf2f((u16)g1[3]) * q2.w;
  sum += bf2f((u16)g1[4]) * q3.x + bf2f((u16)g1[5]) * q3.y +
         bf2f((u16)g1[6]) * q3.z + bf2f((u16)g1[7]) * q3.w;
  sum += __shfl_xor(sum, 1, 64);
  sum += __shfl_xor(sum, 2, 64);
  float v = ((lane & 3) == 0) ? fabsf(sum) : 0.f;
  v += __shfl_xor(v, 4, 64);  v += __shfl_xor(v, 8, 64);
  v += __shfl_xor(v, 16, 64); v += __shfl_xor(v, 32, 64);
  if (lane == 0) redI[wv] = v;
  __syncthreads();
  if (threadIdx.x == 0)
    atomicAdd(acc_inf, redI[0] + redI[1] + redI[2] + redI[3]);
}

__global__ void finalize(const float* __restrict__ acc3, float* __restrict__ out) {
  if (threadIdx.x == 0) {
    out[0] = acc3[0] * (1.f / 65536.f);  // entropy
    out[1] = acc3[2] * (1.f / 65536.f);  // influence
    out[2] = acc3[1] * (1.f / 65536.f);  // concentration
  }
}

extern "C" void kernel_launch(void* const* d_in, const int* in_sizes, int n_in,
                              void* d_out, int out_size, void* d_ws, size_t ws_size,
                              hipStream_t stream) {
  (void)in_sizes; (void)n_in; (void)out_size; (void)ws_size;
  const float* hs  = (const float*)d_in[0];
  const float* ge  = (const float*)d_in[1];
  const float* Wq  = (const float*)d_in[2];
  const float* bq  = (const float*)d_in[3];
  const float* Wk  = (const float*)d_in[4];
  const float* bk  = (const float*)d_in[5];
  const float* Wv  = (const float*)d_in[6];
  const float* bv  = (const float*)d_in[7];
  const float* Wgq = (const float*)d_in[8];
  const float* bgq = (const float*)d_in[9];
  const float* Wgk = (const float*)d_in[10];
  const float* bgk = (const float*)d_in[11];

  char* ws = (char*)d_ws;
  u16* hsB = (u16*)(ws);
  u16* WB  = (u16*)(ws + (size_t)(8 << 20));
  u16* Qb  = (u16*)(ws + (size_t)(16 << 20));
  u16* Kb  = (u16*)(ws + (size_t)(24 << 20));
  u16* Vt  = (u16*)(ws + (size_t)(32 << 20));
  u16* GKb = (u16*)(ws + (size_t)(40 << 20));
  float* gq_part  = (float*)(ws + (size_t)(48 << 20));           // 256 KB
  float* gq_final = (float*)(ws + (size_t)(48 << 20) + 262144);  // 8 KB
  float* acc3     = (float*)(ws + (size_t)(48 << 20) + 524288);
  float* out = (float*)d_out;

  prep<<<3136, 256, 0, stream>>>(hs, Wq, Wk, Wv, Wgk, ge, Wgq, hsB, WB, gq_part);
  gemm_qkvg<<<1025, 256, 0, stream>>>(hsB, WB, bq, bk, bv, bgk, bgq, gq_part,
                                      Qb, Kb, GKb, Vt, gq_final, acc3);
  attn_kernel<<<512, 256, 0, stream>>>(Qb, Kb, Vt, out, acc3);
  gov_kernel<<<1024, 256, 0, stream>>>(GKb, gq_final, acc3 + 2);
  finalize<<<1, 64, 0, stream>>>(acc3, out + 4194304);
}

// Round 7
// 209.531 us; speedup vs baseline: 1.3974x; 1.0617x over previous
//
#include <hip/hip_runtime.h>

// GovernanceAwareAttention on MI355X (gfx950). Round 7.
// Governance bias is constant along key axis -> softmax invariant -> only
// `influence` needs gov_scores. bf16 MFMA projections + flash attention.
//
// R7: (1) PV consumes the QK C-layout DIRECTLY as its B-operand: the 32x32
// C row interleave (reg&3)+8*(reg>>2)+4*half == B-operand k=half*8+j when V
// (A-operand) is read key-split as u*32+sub*8+half*4+j -> paired swizzled
// b64 LDS reads. permlane32_swap/bpermute GONE (they were the 4.2M bank-
// conflict source, 128/wave-iter). (2) influence fused into gemm mat==3
// epilogue (block owns 128 rows x 2 full heads) -> GK never hits memory,
// gov_kernel dispatch removed. acc3 zeroed in prep.

typedef unsigned short u16;
typedef __attribute__((ext_vector_type(8))) short bf16x8;   // 8 bf16 = 4 VGPR
typedef __attribute__((ext_vector_type(4))) float f32x4;
typedef __attribute__((ext_vector_type(16))) float f32x16;
typedef __attribute__((ext_vector_type(2))) float f32x2;
typedef __attribute__((ext_vector_type(4))) u16 u16x4;
typedef __attribute__((ext_vector_type(4))) float float4v;

typedef const __attribute__((address_space(1))) void gvoid_t;
typedef __attribute__((address_space(3))) void lvoid_t;

__device__ __forceinline__ void gl_lds16(const void* g, void* l) {
  // async global->LDS, 16B/lane; LDS dest is wave-uniform base + lane*16
  __builtin_amdgcn_global_load_lds((gvoid_t*)g, (lvoid_t*)l, 16, 0, 0);
}

__device__ __forceinline__ u16 f2bf(float x) {  // RNE f32->bf16
  union { float f; unsigned u; } v; v.f = x;
  unsigned r = v.u + 0x7fffu + ((v.u >> 16) & 1u);
  return (u16)(r >> 16);
}
__device__ __forceinline__ float bf2f(u16 h) {
  union { unsigned u; float f; } v; v.u = ((unsigned)h) << 16; return v.f;
}
// pack two f32 -> two truncated bf16 in one v_perm_b32 (lo in low half)
__device__ __forceinline__ unsigned pk2(float hi, float lo) {
  union { float f; unsigned u; } a, b; a.f = hi; b.f = lo;
  return __builtin_amdgcn_perm(a.u, b.u, 0x07060302u);
}
__device__ __forceinline__ bf16x8 mk8(unsigned a, unsigned b, unsigned c, unsigned d) {
  union { unsigned u[4]; bf16x8 v; } x;
  x.u[0] = a; x.u[1] = b; x.u[2] = c; x.u[3] = d; return x.v;
}

#if defined(__has_builtin)
#if __has_builtin(__builtin_amdgcn_exp2f)
#define EXP2(x) __builtin_amdgcn_exp2f(x)
#endif
#endif
#ifndef EXP2
#define EXP2(x) exp2f(x)
#endif

// ---------------- prep: hs->bf16, W->W^T bf16, gq partials, acc3 zero -------
// grid 3136: [0,2048) conv_hs, [2048,3072) conv_w, [3072,3136) gq partials.
__global__ void prep(const float* __restrict__ hs,
                     const float* __restrict__ W0, const float* __restrict__ W1,
                     const float* __restrict__ W2, const float* __restrict__ W3,
                     const float* __restrict__ ge, const float* __restrict__ Wgq,
                     u16* __restrict__ hsB, u16* __restrict__ WB,
                     float* __restrict__ gq_part, float* __restrict__ acc3) {
  __shared__ __align__(16) u16 T[64][72];
  int bx = blockIdx.x, tid = threadIdx.x;
  if (bx < 2048) {                       // hs f32 [4096x1024] -> bf16, RNE
    int i = bx * 256 + tid;
    const float4v* in4 = (const float4v*)hs;
    float4v a = in4[i * 2], b = in4[i * 2 + 1];
    bf16x8 v;
    v[0] = (short)f2bf(a.x); v[1] = (short)f2bf(a.y);
    v[2] = (short)f2bf(a.z); v[3] = (short)f2bf(a.w);
    v[4] = (short)f2bf(b.x); v[5] = (short)f2bf(b.y);
    v[6] = (short)f2bf(b.z); v[7] = (short)f2bf(b.w);
    *(bf16x8*)&hsB[(size_t)i * 8] = v;
    return;
  }
  if (bx < 3072) {                       // W[k][n] -> WB[mat*1024+n][k], LDS xpose
    int idx = bx - 2048;
    int mat = idx >> 8, sub = idx & 255;
    const float* W = (mat == 0) ? W0 : (mat == 1) ? W1 : (mat == 2) ? W2 : W3;
    int k0 = (sub >> 4) * 64, n0 = (sub & 15) * 64;
#pragma unroll
    for (int p = 0; p < 4; ++p) {
      int chunk = p * 256 + tid;
      int row = chunk >> 4, cp = chunk & 15;
      float4v v = *(const float4v*)&W[(size_t)(k0 + row) * 1024 + n0 + cp * 4];
      u16x4 o; o.x = f2bf(v.x); o.y = f2bf(v.y); o.z = f2bf(v.z); o.w = f2bf(v.w);
      *(u16x4*)&T[row][cp * 4] = o;
    }
    __syncthreads();
#pragma unroll
    for (int p = 0; p < 2; ++p) {
      int chunk = p * 256 + tid;
      int nrow = chunk >> 3, cp = chunk & 7;
      bf16x8 v;
#pragma unroll
      for (int e = 0; e < 8; ++e) v[e] = (short)T[cp * 8 + e][nrow];
      *(bf16x8*)&WB[(size_t)(mat * 1024 + n0 + nrow) * 1024 + k0 + cp * 8] = v;
    }
    return;
  }
  {                                      // gq partial sums (+ acc3 zero)
    int idx = bx - 3072;                 // 64 blocks
    if (idx == 0 && tid < 3) acc3[tid] = 0.f;
    int kb = idx >> 1, b = idx & 1;
    int col0 = tid * 4;
    float4v s = {0.f, 0.f, 0.f, 0.f};
    for (int k = kb * 32; k < kb * 32 + 32; ++k) {
      float g = ge[b * 1024 + k];
      float4v w = *(const float4v*)&Wgq[(size_t)k * 1024 + col0];
      s.x += g * w.x; s.y += g * w.y; s.z += g * w.z; s.w += g * w.w;
    }
    *(float4v*)&gq_part[(size_t)idx * 1024 + col0] = s;  // [kb*2+b][1024]
  }
}

// ---------------- projection GEMM + fused influence --------------------------
// grid 1024. mat==3 blocks compute influence in-register; GK never stored.
__global__ __launch_bounds__(256, 3) void gemm_qkvg(
    const u16* __restrict__ A, const u16* __restrict__ Bw,
    const float* __restrict__ bq, const float* __restrict__ bk,
    const float* __restrict__ bv, const float* __restrict__ bgk,
    const float* __restrict__ bgq, const float* __restrict__ gq_part,
    u16* __restrict__ Qb, u16* __restrict__ Kb, u16* __restrict__ Vt,
    float* __restrict__ acc3) {
  __shared__ __align__(16) u16 As[2][128 * 32];
  __shared__ __align__(16) u16 Bs[2][128 * 32];
  __shared__ float redI[4];
  const int tid = threadIdx.x, lane = tid & 63, wv = tid >> 6;
  const int li = lane & 15, quad = lane >> 4;
  const int bid = blockIdx.x;
  const int nb = bid & 31, mb = bid >> 5;
  const u16* Ap = A + (size_t)(mb * 128) * 1024;
  const u16* Bp = Bw + (size_t)(nb * 128) * 1024;
  const int wm0 = (wv >> 1) * 64, wn0 = (wv & 1) * 64;

  f32x4 acc[4][4];
#pragma unroll
  for (int t = 0; t < 4; ++t)
#pragma unroll
    for (int u = 0; u < 4; ++u) acc[t][u] = (f32x4){0.f, 0.f, 0.f, 0.f};

  // prologue: stage kt=0 into buf 0
#pragma unroll
  for (int jj = 0; jj < 2; ++jj) {
    int j = wv * 2 + jj;
    int row = j * 16 + (lane >> 2);
    int co = lane & 3;
    gl_lds16(Ap + (size_t)row * 1024 + co * 8, &As[0][j * 512]);
    gl_lds16(Bp + (size_t)row * 1024 + co * 8, &Bs[0][j * 512]);
  }

  for (int kt = 0; kt < 32; ++kt) {
    const int cur = kt & 1;
    __syncthreads();                     // drains loads for buf cur
    if (kt < 31) {                       // prefetch kt+1 into other buffer
#pragma unroll
      for (int jj = 0; jj < 2; ++jj) {
        int j = wv * 2 + jj;
        int row = j * 16 + (lane >> 2);
        int co = lane & 3;
        gl_lds16(Ap + (size_t)row * 1024 + (kt + 1) * 32 + co * 8, &As[cur ^ 1][j * 512]);
        gl_lds16(Bp + (size_t)row * 1024 + (kt + 1) * 32 + co * 8, &Bs[cur ^ 1][j * 512]);
      }
    }
    bf16x8 af[4], bf[4];
#pragma unroll
    for (int t = 0; t < 4; ++t)
      af[t] = *(const bf16x8*)&As[cur][(wm0 + t * 16 + li) * 32 + quad * 8];
#pragma unroll
    for (int u = 0; u < 4; ++u)
      bf[u] = *(const bf16x8*)&Bs[cur][(wn0 + u * 16 + li) * 32 + quad * 8];
#pragma unroll
    for (int t = 0; t < 4; ++t)
#pragma unroll
      for (int u = 0; u < 4; ++u)
        acc[t][u] = __builtin_amdgcn_mfma_f32_16x16x32_bf16(af[t], bf[u], acc[t][u], 0, 0, 0);
  }

  const int nbase = nb * 128;
  const int mat = nbase >> 10;           // block never straddles matrices
  if (mat == 3) {
    // ---- fused influence: wave owns 64 rows x 1 full head (64 cols) ----
    const int colbase = nbase & 1023;
    const int bat = (mb * 128) >> 11;    // batch index of this block's rows
    float gqv[4], bgkv[4];
#pragma unroll
    for (int u2 = 0; u2 < 4; ++u2) {
      int col = colbase + wn0 + u2 * 16 + li;
      float g = bgq[col];
      for (int kb = 0; kb < 32; ++kb)
        g += gq_part[(size_t)(kb * 2 + bat) * 1024 + col];
      gqv[u2] = g;
      bgkv[u2] = bgk[col];
    }
    float infl = 0.f;
#pragma unroll
    for (int t = 0; t < 4; ++t)
#pragma unroll
      for (int r = 0; r < 4; ++r) {
        float v = (acc[t][0][r] + bgkv[0]) * gqv[0];
        v = __builtin_fmaf(acc[t][1][r] + bgkv[1], gqv[1], v);
        v = __builtin_fmaf(acc[t][2][r] + bgkv[2], gqv[2], v);
        v = __builtin_fmaf(acc[t][3][r] + bgkv[3], gqv[3], v);
        v += __shfl_xor(v, 1, 64); v += __shfl_xor(v, 2, 64);
        v += __shfl_xor(v, 4, 64); v += __shfl_xor(v, 8, 64);
        infl += fabsf(v);              // all 16 li-lanes hold same v
      }
    infl = (li == 0) ? infl : 0.f;
    infl += __shfl_xor(infl, 16, 64);
    infl += __shfl_xor(infl, 32, 64);
    if (lane == 0) redI[wv] = infl;
    __syncthreads();
    if (tid == 0) atomicAdd(&acc3[2], redI[0] + redI[1] + redI[2] + redI[3]);
  } else if (mat == 2) {
    // V: write transposed Vt[b][col][s] directly, 4 consecutive s per b64
#pragma unroll
    for (int t = 0; t < 4; ++t)
#pragma unroll
      for (int u = 0; u < 4; ++u) {
        int col = (nbase & 1023) + wn0 + u * 16 + li;
        float bb = bv[col];
        int row = mb * 128 + wm0 + t * 16 + quad * 4;  // r=0 row
        int b = row >> 11, s = row & 2047;
        uint2 w;
        w.x = pk2(acc[t][u][1] + bb, acc[t][u][0] + bb);
        w.y = pk2(acc[t][u][3] + bb, acc[t][u][2] + bb);
        *(uint2*)&Vt[(size_t)b * (1024 * 2048) + (size_t)col * 2048 + s] = w;
      }
  } else {
    const float* bias = (mat == 0) ? bq : bk;
    u16* outp = (mat == 0) ? Qb : Kb;
    // Q pre-scaled by 1/sqrt(64) * log2(e) for exp2-based softmax
    const float qscale = (mat == 0) ? 0.18033688f : 1.0f;
#pragma unroll
    for (int t = 0; t < 4; ++t)
#pragma unroll
      for (int u = 0; u < 4; ++u) {
        int col = (nbase & 1023) + wn0 + u * 16 + li;
        float bb = bias[col];
#pragma unroll
        for (int r = 0; r < 4; ++r) {
          int row = mb * 128 + wm0 + t * 16 + quad * 4 + r;
          outp[(size_t)row * 1024 + col] = f2bf((acc[t][u][r] + bb) * qscale);
        }
      }
  }
}

// ---------------- flash attention: 32x32 MFMA, zero-swap P feed --------------
// grid 512 x 256. bh = bx&31 (XCD-L2 locality), qb = bx>>5.
__global__ __launch_bounds__(256, 2) void attn_kernel(
    const u16* __restrict__ Qb, const u16* __restrict__ Kb,
    const u16* __restrict__ Vt, float* __restrict__ out,
    float* __restrict__ acc3 /*[0]=ent,[1]=conc*/) {
  __shared__ __align__(16) u16 Ks[2][128 * 64];   // [key][k], swizzled chunks
  __shared__ __align__(16) u16 Vs[2][64 * 128];   // [d][key], swizzled chunks
  __shared__ float red[8];

  const int tid = threadIdx.x, lane = tid & 63, wv = tid >> 6;
  const int q_l = lane & 31, half = lane >> 5;
  const int bx = blockIdx.x;
  const int bh = bx & 31, qb = bx >> 5;
  const int b = bh >> 4, h = bh & 15;

  const u16* Qp = Qb + (size_t)(b * 2048 + qb * 128 + wv * 32 + q_l) * 1024 + h * 64;
  const u16* Kp = Kb + (size_t)(b * 2048) * 1024 + h * 64;
  const u16* Vp = Vt + (size_t)b * (1024 * 2048) + (size_t)(h * 64) * 2048;

  // Q^T B-frags in registers: lane (q=q_l, half) holds k = s*16 + half*8 + j
  // (already scaled by 0.125*log2e in gemm)
  bf16x8 qf[4];
#pragma unroll
  for (int s = 0; s < 4; ++s)
    qf[s] = *(const bf16x8*)&Qp[s * 16 + half * 8];

  f32x2 mx2 = {-3.0e38f, -3.0e38f}, ps2 = {0.f, 0.f}, es2 = {0.f, 0.f};
  f32x16 accO[2];   // O^T: rows d = dt*32 + (reg&3)+8*(reg>>2)+4*half, col q
#pragma unroll
  for (int dt = 0; dt < 2; ++dt)
#pragma unroll
    for (int r = 0; r < 16; ++r) accO[dt][r] = 0.f;

  // prologue: stage tile 0 into buf 0
#pragma unroll
  for (int jj = 0; jj < 4; ++jj) {
    int j = wv * 4 + jj;
    int row = j * 8 + (lane >> 3);
    int c16 = (lane & 7) ^ (row & 7);
    gl_lds16(Kp + (size_t)row * 1024 + c16 * 8, &Ks[0][j * 512]);
  }
#pragma unroll
  for (int jj = 0; jj < 4; ++jj) {
    int j = wv * 4 + jj;
    int row = j * 4 + (lane >> 4);
    int c16 = (lane & 15) ^ (row & 7);
    gl_lds16(Vp + (size_t)row * 2048 + c16 * 8, &Vs[0][j * 512]);
  }

  for (int kt = 0; kt < 16; ++kt) {
    const int cur = kt & 1;
    __syncthreads();                     // drains tile-kt loads
    if (kt < 15) {                       // prefetch kt+1; compute hides it
      const u16* Kpt = Kp + (size_t)((kt + 1) * 128) * 1024;
#pragma unroll
      for (int jj = 0; jj < 4; ++jj) {
        int j = wv * 4 + jj;
        int row = j * 8 + (lane >> 3);
        int c16 = (lane & 7) ^ (row & 7);
        gl_lds16(Kpt + (size_t)row * 1024 + c16 * 8, &Ks[cur ^ 1][j * 512]);
      }
#pragma unroll
      for (int jj = 0; jj < 4; ++jj) {
        int j = wv * 4 + jj;
        int row = j * 4 + (lane >> 4);
        int c16 = (lane & 15) ^ (row & 7);
        gl_lds16(Vp + (size_t)row * 2048 + (kt + 1) * 128 + c16 * 8, &Vs[cur ^ 1][j * 512]);
      }
    }
    const u16* KsC = &Ks[cur][0];
    const u16* VsC = &Vs[cur][0];

#pragma unroll
    for (int u = 0; u < 4; ++u) {        // 32-key tiles
      // S^T tile = K * Q^T  (A = K-frag: m=key, k = s*16+half*8+j)
      f32x16 c;
#pragma unroll
      for (int r = 0; r < 16; ++r) c[r] = 0.f;
#pragma unroll
      for (int s = 0; s < 4; ++s) {
        int p = (2 * s + half) ^ (q_l & 7);       // key row = u*32+q_l
        bf16x8 a = *(const bf16x8*)&KsC[(u * 32 + q_l) * 64 + p * 8];
        c = __builtin_amdgcn_mfma_f32_32x32x16_bf16(a, qf[s], c, 0, 0, 0);
      }
      // no-max softmax stats (packed f32x2) + native v_exp_f32
#pragma unroll
      for (int r = 0; r < 8; ++r) {
        f32x2 sv = {c[2 * r], c[2 * r + 1]};
        mx2 = __builtin_elementwise_max(mx2, sv);
        f32x2 pe = {EXP2(sv.x), EXP2(sv.y)};
        ps2 += pe;
        es2 += pe * sv;                  // v_pk_fma_f32
        c[2 * r] = pe.x; c[2 * r + 1] = pe.y;
      }
      // P: C regs [4s..4s+3] ARE the B-operand k=half*8+j pattern when V is
      // read key-split (u*32 + sub*8 + half*4 + j). No cross-lane movement.
      bf16x8 bf0 = mk8(pk2(c[1], c[0]),   pk2(c[3], c[2]),
                       pk2(c[5], c[4]),   pk2(c[7], c[6]));    // keys {0-7,8-15} split
      bf16x8 bf1 = mk8(pk2(c[9], c[8]),   pk2(c[11], c[10]),
                       pk2(c[13], c[12]), pk2(c[15], c[14]));  // keys {16-23,24-31}
      // PV: O^T += V^T * P^T  (A = V-frag, paired swizzled b64 reads)
#pragma unroll
      for (int dt = 0; dt < 2; ++dt) {
        int d = dt * 32 + q_l, dx = d & 7;
        const u16* vr = &VsC[d * 128 + half * 4];
        uint2 a0 = *(const uint2*)&vr[((u * 4 + 0) ^ dx) * 8];
        uint2 a1 = *(const uint2*)&vr[((u * 4 + 1) ^ dx) * 8];
        accO[dt] = __builtin_amdgcn_mfma_f32_32x32x16_bf16(
            mk8(a0.x, a0.y, a1.x, a1.y), bf0, accO[dt], 0, 0, 0);
        uint2 a2 = *(const uint2*)&vr[((u * 4 + 2) ^ dx) * 8];
        uint2 a3 = *(const uint2*)&vr[((u * 4 + 3) ^ dx) * 8];
        accO[dt] = __builtin_amdgcn_mfma_f32_32x32x16_bf16(
            mk8(a2.x, a2.y, a3.x, a3.y), bf1, accO[dt], 0, 0, 0);
      }
    }
  }

  // epilogue: each lane owns query q_l (duplicated across half)
  float l_st = ps2.x + ps2.y, e_st = es2.x + es2.y, m_st = fmaxf(mx2.x, mx2.y);
  float lsum = l_st + __shfl_xor(l_st, 32, 64);
  float esum = e_st + __shfl_xor(e_st, 32, 64);
  float mm = fmaxf(m_st, __shfl_xor(m_st, 32, 64));
  float inv = 1.0f / lsum;
  float entw = __logf(lsum) - 0.69314718f * esum * inv;  // s' in log2 units
  float concw = EXP2(mm) * inv;

  float* outp = out + (size_t)(b * 2048 + qb * 128 + wv * 32 + q_l) * 1024 + h * 64;
#pragma unroll
  for (int dt = 0; dt < 2; ++dt)
#pragma unroll
    for (int g = 0; g < 4; ++g) {
      float4v o;
      o.x = accO[dt][4 * g + 0] * inv; o.y = accO[dt][4 * g + 1] * inv;
      o.z = accO[dt][4 * g + 2] * inv; o.w = accO[dt][4 * g + 3] * inv;
      *(float4v*)&outp[dt * 32 + 8 * g + 4 * half] = o;
    }

#pragma unroll
  for (int off = 1; off < 64; off <<= 1) {
    entw += __shfl_xor(entw, off, 64);
    concw += __shfl_xor(concw, off, 64);
  }
  if (lane == 0) { red[wv] = entw * 0.5f; red[4 + wv] = concw * 0.5f; }  // /2 dup
  __syncthreads();
  if (tid == 0) {
    atomicAdd(&acc3[0], red[0] + red[1] + red[2] + red[3]);
    atomicAdd(&acc3[1], red[4] + red[5] + red[6] + red[7]);
  }
}

__global__ void finalize(const float* __restrict__ acc3, float* __restrict__ out) {
  if (threadIdx.x == 0) {
    out[0] = acc3[0] * (1.f / 65536.f);  // entropy
    out[1] = acc3[2] * (1.f / 65536.f);  // influence
    out[2] = acc3[1] * (1.f / 65536.f);  // concentration
  }
}

extern "C" void kernel_launch(void* const* d_in, const int* in_sizes, int n_in,
                              void* d_out, int out_size, void* d_ws, size_t ws_size,
                              hipStream_t stream) {
  (void)in_sizes; (void)n_in; (void)out_size; (void)ws_size;
  const float* hs  = (const float*)d_in[0];
  const float* ge  = (const float*)d_in[1];
  const float* Wq  = (const float*)d_in[2];
  const float* bq  = (const float*)d_in[3];
  const float* Wk  = (const float*)d_in[4];
  const float* bk  = (const float*)d_in[5];
  const float* Wv  = (const float*)d_in[6];
  const float* bv  = (const float*)d_in[7];
  const float* Wgq = (const float*)d_in[8];
  const float* bgq = (const float*)d_in[9];
  const float* Wgk = (const float*)d_in[10];
  const float* bgk = (const float*)d_in[11];

  char* ws = (char*)d_ws;
  u16* hsB = (u16*)(ws);
  u16* WB  = (u16*)(ws + (size_t)(8 << 20));
  u16* Qb  = (u16*)(ws + (size_t)(16 << 20));
  u16* Kb  = (u16*)(ws + (size_t)(24 << 20));
  u16* Vt  = (u16*)(ws + (size_t)(32 << 20));
  float* gq_part = (float*)(ws + (size_t)(48 << 20));            // 256 KB
  float* acc3    = (float*)(ws + (size_t)(48 << 20) + 524288);
  float* out = (float*)d_out;

  prep<<<3136, 256, 0, stream>>>(hs, Wq, Wk, Wv, Wgk, ge, Wgq, hsB, WB, gq_part, acc3);
  gemm_qkvg<<<1024, 256, 0, stream>>>(hsB, WB, bq, bk, bv, bgk, bgq, gq_part,
                                      Qb, Kb, Vt, acc3);
  attn_kernel<<<512, 256, 0, stream>>>(Qb, Kb, Vt, out, acc3);
  finalize<<<1, 64, 0, stream>>>(acc3, out + 4194304);
}

// Round 8
// 207.983 us; speedup vs baseline: 1.4078x; 1.0074x over previous
//
#include <hip/hip_runtime.h>

// GovernanceAwareAttention on MI355X (gfx950). Round 8.
// Governance bias is constant along key axis -> softmax invariant -> only
// `influence` needs gov_scores (fused into gemm). bf16 MFMA + flash attn.
//
// R8: conflict-free attention LDS. Root cause found in R7 post-mortem: K/V
// LDS rows were 128B (≡ 0 mod 32 banks) so all 32 A-operand rows start at
// bank 0 -> structural 4-way conflicts on every read (chunk-XOR can't fix).
// New layouts: Kt4[b][h][g=k/4][s][4] and Vt4[b][g=s/4][d][4] in global
// (written by gemm epilogues), LDS tiles are [g-column][row] at 8B granule
// (column == the contiguous unit global_load_lds writes), with row stored at
// physical r^(8*half-parity-of-g) so the two wave-halves hit different
// banks. All K/V reads: bank = 2*row mod 32, 2 lanes/bank = free.

typedef unsigned short u16;
typedef __attribute__((ext_vector_type(8))) short bf16x8;   // 8 bf16 = 4 VGPR
typedef __attribute__((ext_vector_type(4))) float f32x4;
typedef __attribute__((ext_vector_type(16))) float f32x16;
typedef __attribute__((ext_vector_type(2))) float f32x2;
typedef __attribute__((ext_vector_type(4))) u16 u16x4;
typedef __attribute__((ext_vector_type(4))) float float4v;

typedef const __attribute__((address_space(1))) void gvoid_t;
typedef __attribute__((address_space(3))) void lvoid_t;

__device__ __forceinline__ void gl_lds16(const void* g, void* l) {
  // async global->LDS, 16B/lane; LDS dest is wave-uniform base + lane*16
  __builtin_amdgcn_global_load_lds((gvoid_t*)g, (lvoid_t*)l, 16, 0, 0);
}

__device__ __forceinline__ u16 f2bf(float x) {  // RNE f32->bf16
  union { float f; unsigned u; } v; v.f = x;
  unsigned r = v.u + 0x7fffu + ((v.u >> 16) & 1u);
  return (u16)(r >> 16);
}
// pack two f32 -> two truncated bf16 in one v_perm_b32 (lo in low half)
__device__ __forceinline__ unsigned pk2(float hi, float lo) {
  union { float f; unsigned u; } a, b; a.f = hi; b.f = lo;
  return __builtin_amdgcn_perm(a.u, b.u, 0x07060302u);
}
__device__ __forceinline__ bf16x8 mk8(unsigned a, unsigned b, unsigned c, unsigned d) {
  union { unsigned u[4]; bf16x8 v; } x;
  x.u[0] = a; x.u[1] = b; x.u[2] = c; x.u[3] = d; return x.v;
}

#if defined(__has_builtin)
#if __has_builtin(__builtin_amdgcn_exp2f)
#define EXP2(x) __builtin_amdgcn_exp2f(x)
#endif
#endif
#ifndef EXP2
#define EXP2(x) exp2f(x)
#endif

// ---------------- prep: hs->bf16, W->W^T bf16, gq partials, acc3 zero -------
// grid 3136: [0,2048) conv_hs, [2048,3072) conv_w, [3072,3136) gq partials.
__global__ void prep(const float* __restrict__ hs,
                     const float* __restrict__ W0, const float* __restrict__ W1,
                     const float* __restrict__ W2, const float* __restrict__ W3,
                     const float* __restrict__ ge, const float* __restrict__ Wgq,
                     u16* __restrict__ hsB, u16* __restrict__ WB,
                     float* __restrict__ gq_part, float* __restrict__ acc3) {
  __shared__ __align__(16) u16 T[64][72];
  int bx = blockIdx.x, tid = threadIdx.x;
  if (bx < 2048) {                       // hs f32 [4096x1024] -> bf16, RNE
    int i = bx * 256 + tid;
    const float4v* in4 = (const float4v*)hs;
    float4v a = in4[i * 2], b = in4[i * 2 + 1];
    bf16x8 v;
    v[0] = (short)f2bf(a.x); v[1] = (short)f2bf(a.y);
    v[2] = (short)f2bf(a.z); v[3] = (short)f2bf(a.w);
    v[4] = (short)f2bf(b.x); v[5] = (short)f2bf(b.y);
    v[6] = (short)f2bf(b.z); v[7] = (short)f2bf(b.w);
    *(bf16x8*)&hsB[(size_t)i * 8] = v;
    return;
  }
  if (bx < 3072) {                       // W[k][n] -> WB[mat*1024+n][k], LDS xpose
    int idx = bx - 2048;
    int mat = idx >> 8, sub = idx & 255;
    const float* W = (mat == 0) ? W0 : (mat == 1) ? W1 : (mat == 2) ? W2 : W3;
    int k0 = (sub >> 4) * 64, n0 = (sub & 15) * 64;
#pragma unroll
    for (int p = 0; p < 4; ++p) {
      int chunk = p * 256 + tid;
      int row = chunk >> 4, cp = chunk & 15;
      float4v v = *(const float4v*)&W[(size_t)(k0 + row) * 1024 + n0 + cp * 4];
      u16x4 o; o.x = f2bf(v.x); o.y = f2bf(v.y); o.z = f2bf(v.z); o.w = f2bf(v.w);
      *(u16x4*)&T[row][cp * 4] = o;
    }
    __syncthreads();
#pragma unroll
    for (int p = 0; p < 2; ++p) {
      int chunk = p * 256 + tid;
      int nrow = chunk >> 3, cp = chunk & 7;
      bf16x8 v;
#pragma unroll
      for (int e = 0; e < 8; ++e) v[e] = (short)T[cp * 8 + e][nrow];
      *(bf16x8*)&WB[(size_t)(mat * 1024 + n0 + nrow) * 1024 + k0 + cp * 8] = v;
    }
    return;
  }
  {                                      // gq partial sums (+ acc3 zero)
    int idx = bx - 3072;                 // 64 blocks
    if (idx == 0 && tid < 3) acc3[tid] = 0.f;
    int kb = idx >> 1, b = idx & 1;
    int col0 = tid * 4;
    float4v s = {0.f, 0.f, 0.f, 0.f};
    for (int k = kb * 32; k < kb * 32 + 32; ++k) {
      float g = ge[b * 1024 + k];
      float4v w = *(const float4v*)&Wgq[(size_t)k * 1024 + col0];
      s.x += g * w.x; s.y += g * w.y; s.z += g * w.z; s.w += g * w.w;
    }
    *(float4v*)&gq_part[(size_t)idx * 1024 + col0] = s;  // [kb*2+b][1024]
  }
}

// ---------------- projection GEMM + fused influence --------------------------
// grid 1024. mat==3 blocks compute influence in-register; GK never stored.
// K -> Kt4[b][h][g=k/4][s:2048][4];  V -> Vt4[b][g=s/4][d:1024][4].
__global__ __launch_bounds__(256, 3) void gemm_qkvg(
    const u16* __restrict__ A, const u16* __restrict__ Bw,
    const float* __restrict__ bq, const float* __restrict__ bk,
    const float* __restrict__ bv, const float* __restrict__ bgk,
    const float* __restrict__ bgq, const float* __restrict__ gq_part,
    u16* __restrict__ Qb, u16* __restrict__ Kt4, u16* __restrict__ Vt4,
    float* __restrict__ acc3) {
  __shared__ __align__(16) u16 As[2][128 * 32];
  __shared__ __align__(16) u16 Bs[2][128 * 32];
  __shared__ float redI[4];
  const int tid = threadIdx.x, lane = tid & 63, wv = tid >> 6;
  const int li = lane & 15, quad = lane >> 4;
  const int bid = blockIdx.x;
  const int nb = bid & 31, mb = bid >> 5;
  const u16* Ap = A + (size_t)(mb * 128) * 1024;
  const u16* Bp = Bw + (size_t)(nb * 128) * 1024;
  const int wm0 = (wv >> 1) * 64, wn0 = (wv & 1) * 64;

  f32x4 acc[4][4];
#pragma unroll
  for (int t = 0; t < 4; ++t)
#pragma unroll
    for (int u = 0; u < 4; ++u) acc[t][u] = (f32x4){0.f, 0.f, 0.f, 0.f};

  // prologue: stage kt=0 into buf 0
#pragma unroll
  for (int jj = 0; jj < 2; ++jj) {
    int j = wv * 2 + jj;
    int row = j * 16 + (lane >> 2);
    int co = lane & 3;
    gl_lds16(Ap + (size_t)row * 1024 + co * 8, &As[0][j * 512]);
    gl_lds16(Bp + (size_t)row * 1024 + co * 8, &Bs[0][j * 512]);
  }

  for (int kt = 0; kt < 32; ++kt) {
    const int cur = kt & 1;
    __syncthreads();                     // drains loads for buf cur
    if (kt < 31) {                       // prefetch kt+1 into other buffer
#pragma unroll
      for (int jj = 0; jj < 2; ++jj) {
        int j = wv * 2 + jj;
        int row = j * 16 + (lane >> 2);
        int co = lane & 3;
        gl_lds16(Ap + (size_t)row * 1024 + (kt + 1) * 32 + co * 8, &As[cur ^ 1][j * 512]);
        gl_lds16(Bp + (size_t)row * 1024 + (kt + 1) * 32 + co * 8, &Bs[cur ^ 1][j * 512]);
      }
    }
    bf16x8 af[4], bf[4];
#pragma unroll
    for (int t = 0; t < 4; ++t)
      af[t] = *(const bf16x8*)&As[cur][(wm0 + t * 16 + li) * 32 + quad * 8];
#pragma unroll
    for (int u = 0; u < 4; ++u)
      bf[u] = *(const bf16x8*)&Bs[cur][(wn0 + u * 16 + li) * 32 + quad * 8];
#pragma unroll
    for (int t = 0; t < 4; ++t)
#pragma unroll
      for (int u = 0; u < 4; ++u)
        acc[t][u] = __builtin_amdgcn_mfma_f32_16x16x32_bf16(af[t], bf[u], acc[t][u], 0, 0, 0);
  }

  const int nbase = nb * 128;
  const int mat = nbase >> 10;           // block never straddles matrices
  if (mat == 3) {
    // ---- fused influence: wave owns 64 rows x 1 full head (64 cols) ----
    const int colbase = nbase & 1023;
    const int bat = (mb * 128) >> 11;    // batch index of this block's rows
    float gqv[4], bgkv[4];
#pragma unroll
    for (int u2 = 0; u2 < 4; ++u2) {
      int col = colbase + wn0 + u2 * 16 + li;
      float g = bgq[col];
      for (int kb = 0; kb < 32; ++kb)
        g += gq_part[(size_t)(kb * 2 + bat) * 1024 + col];
      gqv[u2] = g;
      bgkv[u2] = bgk[col];
    }
    float infl = 0.f;
#pragma unroll
    for (int t = 0; t < 4; ++t)
#pragma unroll
      for (int r = 0; r < 4; ++r) {
        float v = (acc[t][0][r] + bgkv[0]) * gqv[0];
        v = __builtin_fmaf(acc[t][1][r] + bgkv[1], gqv[1], v);
        v = __builtin_fmaf(acc[t][2][r] + bgkv[2], gqv[2], v);
        v = __builtin_fmaf(acc[t][3][r] + bgkv[3], gqv[3], v);
        v += __shfl_xor(v, 1, 64); v += __shfl_xor(v, 2, 64);
        v += __shfl_xor(v, 4, 64); v += __shfl_xor(v, 8, 64);
        infl += fabsf(v);              // all 16 li-lanes hold same v
      }
    infl = (li == 0) ? infl : 0.f;
    infl += __shfl_xor(infl, 16, 64);
    infl += __shfl_xor(infl, 32, 64);
    if (lane == 0) redI[wv] = infl;
    __syncthreads();
    if (tid == 0) atomicAdd(&acc3[2], redI[0] + redI[1] + redI[2] + redI[3]);
  } else if (mat == 2) {
    // V -> Vt4[b][g=s/4][d:1024][4s], one b64 per (t,u)
#pragma unroll
    for (int t = 0; t < 4; ++t)
#pragma unroll
      for (int u = 0; u < 4; ++u) {
        int col = (nbase & 1023) + wn0 + u * 16 + li;
        float bb = bv[col];
        int row = mb * 128 + wm0 + t * 16 + quad * 4;  // s%4 == 0
        int b = row >> 11, s = row & 2047, g = s >> 2;
        uint2 w;
        w.x = pk2(acc[t][u][1] + bb, acc[t][u][0] + bb);
        w.y = pk2(acc[t][u][3] + bb, acc[t][u][2] + bb);
        *(uint2*)&Vt4[(((size_t)b * 512 + g) * 1024 + col) * 4] = w;
      }
  } else if (mat == 1) {
    // K -> Kt4[b][h][g=k/4][s:2048][4k], scalar stores (8B-local per r)
#pragma unroll
    for (int t = 0; t < 4; ++t)
#pragma unroll
      for (int u = 0; u < 4; ++u) {
        int col = (nbase & 1023) + wn0 + u * 16 + li;
        int h = col >> 6, g = (col & 63) >> 2, r4 = col & 3;
        float bb = bk[col];
        u16* base = &Kt4[(((size_t)(0 * 16 + h) * 16 + g) * 2048) * 4 + r4];
#pragma unroll
        for (int r = 0; r < 4; ++r) {
          int row = mb * 128 + wm0 + t * 16 + quad * 4 + r;
          int b = row >> 11, s = row & 2047;
          base[((size_t)b * 16 * 16 * 2048 + s) * 4] = f2bf(acc[t][u][r] + bb);
        }
      }
  } else {
    // Q (pre-scaled by 1/sqrt(64) * log2(e) for exp2-based softmax)
#pragma unroll
    for (int t = 0; t < 4; ++t)
#pragma unroll
      for (int u = 0; u < 4; ++u) {
        int col = (nbase & 1023) + wn0 + u * 16 + li;
        float bb = bq[col];
#pragma unroll
        for (int r = 0; r < 4; ++r) {
          int row = mb * 128 + wm0 + t * 16 + quad * 4 + r;
          Qb[(size_t)row * 1024 + col] = f2bf((acc[t][u][r] + bb) * 0.18033688f);
        }
      }
  }
}

// ---------------- flash attention: 32x32 MFMA, conflict-free LDS -------------
// grid 512 x 256. bh = bx&31 (XCD-L2 locality), qb = bx>>5.
__global__ __launch_bounds__(256, 2) void attn_kernel(
    const u16* __restrict__ Qb, const u16* __restrict__ Kt4,
    const u16* __restrict__ Vt4, float* __restrict__ out,
    float* __restrict__ acc3 /*[0]=ent,[1]=conc*/) {
  __shared__ __align__(16) u16 Ks[2][8192];   // [g:16][s_phys:128][4k]
  __shared__ __align__(16) u16 Vs[2][8192];   // [g:32][d_phys:64][4s]
  __shared__ float red[8];

  const int tid = threadIdx.x, lane = tid & 63, wv = tid >> 6;
  const int q_l = lane & 31, half = lane >> 5;
  const int x8 = half << 3;              // row-XOR for bank spread
  const int bx = blockIdx.x;
  const int bh = bx & 31, qb = bx >> 5;
  const int b = bh >> 4, h = bh & 15;

  const u16* Qp = Qb + (size_t)(b * 2048 + qb * 128 + wv * 32 + q_l) * 1024 + h * 64;
  const u16* Kp4 = Kt4 + ((size_t)(b * 16 + h) * 16) * 2048 * 4;
  const u16* Vp4 = Vt4 + ((size_t)b * 512 * 1024 + h * 64) * 4;

  // Q^T B-frags in registers: lane (q=q_l, half) holds k = s*16 + half*8 + j
  bf16x8 qf[4];
#pragma unroll
  for (int s = 0; s < 4; ++s)
    qf[s] = *(const bf16x8*)&Qp[s * 16 + half * 8];

  f32x2 mx2 = {-3.0e38f, -3.0e38f}, ps2 = {0.f, 0.f}, es2 = {0.f, 0.f};
  f32x16 accO[2];   // O^T: rows d = dt*32 + (reg&3)+8*(reg>>2)+4*half, col q
#pragma unroll
  for (int dt = 0; dt < 2; ++dt)
#pragma unroll
    for (int r = 0; r < 16; ++r) accO[dt][r] = 0.f;

  // staging lane->source indices (XOR-8 so wave-halves hit different banks)
  const int ksrc = (2 * lane);           // ^x8g per column below
  const int vlane_d = 2 * (lane & 31);

  // prologue: stage tile 0 into buf 0
#pragma unroll
  for (int jj = 0; jj < 4; ++jj) {
    int g = wv * 4 + jj;
    int xg = ((g >> 1) & 1) << 3;
    gl_lds16(Kp4 + ((size_t)g * 2048 + (ksrc ^ xg)) * 4, &Ks[0][g * 512]);
  }
#pragma unroll
  for (int jj = 0; jj < 4; ++jj) {
    int j = wv * 4 + jj;
    int g = 2 * j + (lane >> 5);
    int xg = (g & 1) << 3;
    gl_lds16(Vp4 + ((size_t)g * 1024 + (vlane_d ^ xg)) * 4, &Vs[0][j * 512]);
  }

  for (int kt = 0; kt < 16; ++kt) {
    const int cur = kt & 1;
    __syncthreads();                     // drains tile-kt loads
    if (kt < 15) {                       // prefetch kt+1; compute hides it
#pragma unroll
      for (int jj = 0; jj < 4; ++jj) {
        int g = wv * 4 + jj;
        int xg = ((g >> 1) & 1) << 3;
        gl_lds16(Kp4 + ((size_t)g * 2048 + (kt + 1) * 128 + (ksrc ^ xg)) * 4,
                 &Ks[cur ^ 1][g * 512]);
      }
#pragma unroll
      for (int jj = 0; jj < 4; ++jj) {
        int j = wv * 4 + jj;
        int g = 2 * j + (lane >> 5);
        int xg = (g & 1) << 3;
        gl_lds16(Vp4 + ((size_t)((kt + 1) * 32 + g) * 1024 + (vlane_d ^ xg)) * 4,
                 &Vs[cur ^ 1][j * 512]);
      }
    }
    const u16* KsC = &Ks[cur][0];
    const u16* VsC = &Vs[cur][0];

#pragma unroll
    for (int u = 0; u < 4; ++u) {        // 32-key tiles
      // S^T tile = K * Q^T  (A = K-frag: m=key, k = s*16+half*8+j)
      const int keyp = (u * 32 + q_l) ^ x8;    // physical row (XOR-8 stored)
      f32x16 c;
#pragma unroll
      for (int r = 0; r < 16; ++r) c[r] = 0.f;
#pragma unroll
      for (int s = 0; s < 4; ++s) {
        int g0 = s * 4 + half * 2;
        uint2 k0 = *(const uint2*)&KsC[g0 * 512 + keyp * 4];
        uint2 k1 = *(const uint2*)&KsC[(g0 + 1) * 512 + keyp * 4];
        c = __builtin_amdgcn_mfma_f32_32x32x16_bf16(
            mk8(k0.x, k0.y, k1.x, k1.y), qf[s], c, 0, 0, 0);
      }
      // no-max softmax stats (packed f32x2) + native v_exp_f32
#pragma unroll
      for (int r = 0; r < 8; ++r) {
        f32x2 sv = {c[2 * r], c[2 * r + 1]};
        mx2 = __builtin_elementwise_max(mx2, sv);
        f32x2 pe = {EXP2(sv.x), EXP2(sv.y)};
        ps2 += pe;
        es2 += pe * sv;                  // v_pk_fma_f32
        c[2 * r] = pe.x; c[2 * r + 1] = pe.y;
      }
      // P: C regs ARE the B-operand pattern; A (V) read key-split to match
      bf16x8 bf0 = mk8(pk2(c[1], c[0]),   pk2(c[3], c[2]),
                       pk2(c[5], c[4]),   pk2(c[7], c[6]));    // keys {0-3,8-11}+4h
      bf16x8 bf1 = mk8(pk2(c[9], c[8]),   pk2(c[11], c[10]),
                       pk2(c[13], c[12]), pk2(c[15], c[14]));  // keys {16-19,24-27}+4h
      // PV: O^T += V^T * P^T  (A = V-frag from [g][d] columns, XOR-8 rows)
#pragma unroll
      for (int dt = 0; dt < 2; ++dt) {
        int dp = (dt * 32 + q_l) ^ x8;   // physical d row
        uint2 v0 = *(const uint2*)&VsC[(u * 8 + half) * 256 + dp * 4];
        uint2 v1 = *(const uint2*)&VsC[(u * 8 + 2 + half) * 256 + dp * 4];
        accO[dt] = __builtin_amdgcn_mfma_f32_32x32x16_bf16(
            mk8(v0.x, v0.y, v1.x, v1.y), bf0, accO[dt], 0, 0, 0);
        uint2 v2 = *(const uint2*)&VsC[(u * 8 + 4 + half) * 256 + dp * 4];
        uint2 v3 = *(const uint2*)&VsC[(u * 8 + 6 + half) * 256 + dp * 4];
        accO[dt] = __builtin_amdgcn_mfma_f32_32x32x16_bf16(
            mk8(v2.x, v2.y, v3.x, v3.y), bf1, accO[dt], 0, 0, 0);
      }
    }
  }

  // epilogue: each lane owns query q_l (duplicated across half)
  float l_st = ps2.x + ps2.y, e_st = es2.x + es2.y, m_st = fmaxf(mx2.x, mx2.y);
  float lsum = l_st + __shfl_xor(l_st, 32, 64);
  float esum = e_st + __shfl_xor(e_st, 32, 64);
  float mm = fmaxf(m_st, __shfl_xor(m_st, 32, 64));
  float inv = 1.0f / lsum;
  float entw = __logf(lsum) - 0.69314718f * esum * inv;  // s' in log2 units
  float concw = EXP2(mm) * inv;

  float* outp = out + (size_t)(b * 2048 + qb * 128 + wv * 32 + q_l) * 1024 + h * 64;
#pragma unroll
  for (int dt = 0; dt < 2; ++dt)
#pragma unroll
    for (int g = 0; g < 4; ++g) {
      float4v o;
      o.x = accO[dt][4 * g + 0] * inv; o.y = accO[dt][4 * g + 1] * inv;
      o.z = accO[dt][4 * g + 2] * inv; o.w = accO[dt][4 * g + 3] * inv;
      *(float4v*)&outp[dt * 32 + 8 * g + 4 * half] = o;
    }

#pragma unroll
  for (int off = 1; off < 64; off <<= 1) {
    entw += __shfl_xor(entw, off, 64);
    concw += __shfl_xor(concw, off, 64);
  }
  if (lane == 0) { red[wv] = entw * 0.5f; red[4 + wv] = concw * 0.5f; }  // /2 dup
  __syncthreads();
  if (tid == 0) {
    atomicAdd(&acc3[0], red[0] + red[1] + red[2] + red[3]);
    atomicAdd(&acc3[1], red[4] + red[5] + red[6] + red[7]);
  }
}

__global__ void finalize(const float* __restrict__ acc3, float* __restrict__ out) {
  if (threadIdx.x == 0) {
    out[0] = acc3[0] * (1.f / 65536.f);  // entropy
    out[1] = acc3[2] * (1.f / 65536.f);  // influence
    out[2] = acc3[1] * (1.f / 65536.f);  // concentration
  }
}

extern "C" void kernel_launch(void* const* d_in, const int* in_sizes, int n_in,
                              void* d_out, int out_size, void* d_ws, size_t ws_size,
                              hipStream_t stream) {
  (void)in_sizes; (void)n_in; (void)out_size; (void)ws_size;
  const float* hs  = (const float*)d_in[0];
  const float* ge  = (const float*)d_in[1];
  const float* Wq  = (const float*)d_in[2];
  const float* bq  = (const float*)d_in[3];
  const float* Wk  = (const float*)d_in[4];
  const float* bk  = (const float*)d_in[5];
  const float* Wv  = (const float*)d_in[6];
  const float* bv  = (const float*)d_in[7];
  const float* Wgq = (const float*)d_in[8];
  const float* bgq = (const float*)d_in[9];
  const float* Wgk = (const float*)d_in[10];
  const float* bgk = (const float*)d_in[11];

  char* ws = (char*)d_ws;
  u16* hsB  = (u16*)(ws);
  u16* WB   = (u16*)(ws + (size_t)(8 << 20));
  u16* Qb   = (u16*)(ws + (size_t)(16 << 20));
  u16* Kt4  = (u16*)(ws + (size_t)(24 << 20));
  u16* Vt4  = (u16*)(ws + (size_t)(32 << 20));
  float* gq_part = (float*)(ws + (size_t)(48 << 20));            // 256 KB
  float* acc3    = (float*)(ws + (size_t)(48 << 20) + 524288);
  float* out = (float*)d_out;

  prep<<<3136, 256, 0, stream>>>(hs, Wq, Wk, Wv, Wgk, ge, Wgq, hsB, WB, gq_part, acc3);
  gemm_qkvg<<<1024, 256, 0, stream>>>(hsB, WB, bq, bk, bv, bgk, bgq, gq_part,
                                      Qb, Kt4, Vt4, acc3);
  attn_kernel<<<512, 256, 0, stream>>>(Qb, Kt4, Vt4, out, acc3);
  finalize<<<1, 64, 0, stream>>>(acc3, out + 4194304);
}